// Round 6
// baseline (2017.779 us; speedup 1.0000x reference)
//
#include <hip/hip_runtime.h>
#include <stdint.h>

#define DEVI __device__ __forceinline__
#define FENCE() asm volatile("" ::: "memory")
#define BAR() do{ FENCE(); __builtin_amdgcn_s_barrier(); FENCE(); }while(0)

typedef short short8 __attribute__((ext_vector_type(8)));
typedef short short4v __attribute__((ext_vector_type(4)));
typedef float f32x4 __attribute__((ext_vector_type(4)));

DEVI float bf2f(unsigned short s){ union{unsigned u; float f;} x; x.u = ((unsigned)s)<<16; return x.f; }
DEVI unsigned short f2bf(float f){ union{float f; unsigned u;} x; x.f=f; unsigned r = x.u + 0x7fff + ((x.u>>16)&1); return (unsigned short)(r>>16); }

DEVI void gload_lds16(const void* g, void* l){
  __builtin_amdgcn_global_load_lds((const __attribute__((address_space(1))) unsigned int*)g,
                                   (__attribute__((address_space(3))) unsigned int*)l, 16, 0, 0);
}

// ---------------------------------------------------------------------------
// fp32 [K][N] (optionally batched z) -> bf16 [N][K]
__global__ __launch_bounds__(256)
void transpose_cvt(const float* __restrict__ in, unsigned short* __restrict__ out, int K, int N)
{
  __shared__ float tile[32][33];
  size_t zoff = (size_t)blockIdx.z * K * N;
  const float* src = in + zoff;
  unsigned short* dst = out + zoff;
  int kb = blockIdx.y*32, nb = blockIdx.x*32;
  int t = threadIdx.x;
  int tr = t>>3, tc = (t&7)*4;
  float4 v = *(const float4*)(src + (size_t)(kb+tr)*N + nb + tc);
  tile[tr][tc+0]=v.x; tile[tr][tc+1]=v.y; tile[tr][tc+2]=v.z; tile[tr][tc+3]=v.w;
  __syncthreads();
  short4v ov;
  ov[0] = (short)f2bf(tile[tc+0][tr]);
  ov[1] = (short)f2bf(tile[tc+1][tr]);
  ov[2] = (short)f2bf(tile[tc+2][tr]);
  ov[3] = (short)f2bf(tile[tc+3][tr]);
  *(short4v*)(dst + (size_t)(nb+tr)*K + kb + tc) = ov;
}

// ---------------------------------------------------------------------------
// w1 fp32 [2048][4096] -> permuted bf16 [4096][2048]: permuted row np holds
// source col c(np) = (np&16 ? 2048 : 0) + ((np>>5)<<4) + (np&15)
__global__ __launch_bounds__(256)
void transpose_cvt_w1(const float* __restrict__ w1, unsigned short* __restrict__ outp)
{
  __shared__ float tile[32][33];
  int e = blockIdx.z;
  const float* src = w1 + (size_t)e*2048*4096;
  unsigned short* dst = outp + (size_t)e*4096*2048;
  int np0 = blockIdx.x*32;
  int k0 = blockIdx.y*32;
  int g = np0 >> 5;
  int t = threadIdx.x;
  int tr = t>>3, tc = (t&7)*4;
  int srccol = (tc < 16) ? (g*16 + tc) : (2048 + g*16 + (tc-16));
  float4 v = *(const float4*)(src + (size_t)(k0+tr)*4096 + srccol);
  tile[tr][tc+0]=v.x; tile[tr][tc+1]=v.y; tile[tr][tc+2]=v.z; tile[tr][tc+3]=v.w;
  __syncthreads();
  short4v ov;
  ov[0] = (short)f2bf(tile[tc+0][tr]);
  ov[1] = (short)f2bf(tile[tc+1][tr]);
  ov[2] = (short)f2bf(tile[tc+2][tr]);
  ov[3] = (short)f2bf(tile[tc+3][tr]);
  *(short4v*)(dst + (size_t)(np0+tr)*2048 + k0 + tc) = ov;
}

// ---------------------------------------------------------------------------
__global__ __launch_bounds__(256)
void rmsnorm_k(const float* __restrict__ x, const float* __restrict__ gw,
               const float* __restrict__ bw, unsigned short* __restrict__ xn)
{
  int row = blockIdx.x*4 + (threadIdx.x>>6);
  int lane = threadIdx.x & 63;
  const float* xr = x + (size_t)row*512 + lane*8;
  float4 a = *(const float4*)xr;
  float4 c = *(const float4*)(xr+4);
  float ss = a.x*a.x+a.y*a.y+a.z*a.z+a.w*a.w + c.x*c.x+c.y*c.y+c.z*c.z+c.w*c.w;
  #pragma unroll
  for (int m=1;m<64;m<<=1) ss += __shfl_xor(ss, m);
  float inv = 1.0f / sqrtf(ss*(1.f/512.f) + 1e-6f);
  const float* gr = gw + lane*8; const float* br = bw + lane*8;
  float4 g0=*(const float4*)gr, g1=*(const float4*)(gr+4);
  float4 b0=*(const float4*)br, b1=*(const float4*)(br+4);
  short8 o;
  o[0]=(short)f2bf(a.x*inv*g0.x + b0.x);
  o[1]=(short)f2bf(a.y*inv*g0.y + b0.y);
  o[2]=(short)f2bf(a.z*inv*g0.z + b0.z);
  o[3]=(short)f2bf(a.w*inv*g0.w + b0.w);
  o[4]=(short)f2bf(c.x*inv*g1.x + b1.x);
  o[5]=(short)f2bf(c.y*inv*g1.y + b1.y);
  o[6]=(short)f2bf(c.z*inv*g1.z + b1.z);
  o[7]=(short)f2bf(c.w*inv*g1.w + b1.w);
  *(short8*)(xn + (size_t)row*512 + lane*8) = o;
}

// ---------------------------------------------------------------------------
// m201-faithful 256x256 tile engine: 512 thr / 8 waves (2Mx4N), per-wave
// 128x64 out, BK=64, 2 LDS K-tile slots (128 KiB), 4 phases/K-tile with
// per-phase {1-quadrant ds_read || 1 half-tile stage}, counted vmcnt(4).
// Stage schedule: P0: kt+1 A-lo+A-hi; P1: kt+2 B-lo; P2: kt+2 B-hi; P3: vmcnt.
// All stages write regions whose readers passed a barrier (deterministic).
// EPI: 0 = fp32 out + bias; 1 = bf16 out + bias; 2 = fused SwiGLU (permuted
// W1 cols, bias[0..2047]=a-bias @scol, bias[2048..]=gate-bias) -> bf16 [*,2048]
#define READ_AFR(Q) do{ \
  _Pragma("unroll") \
  for (int m2=0;m2<2;m2++){ \
    int rt = wm*128 + ((Q)*2+m2)*16 + lrow; \
    _Pragma("unroll") \
    for (int kk=0;kk<2;kk++) \
      afr[m2][kk] = *(const short8*)(sA + rt*128 + (((lg+kk*4)^(rt&7))<<4)); \
  } \
}while(0)

#define QUADP(Q) do{ \
  __builtin_amdgcn_s_setprio(1); \
  _Pragma("unroll") \
  for (int m2=0;m2<2;m2++){ \
    _Pragma("unroll") \
    for (int n=0;n<4;n++){ \
      _Pragma("unroll") \
      for (int kk=0;kk<2;kk++) \
        acc[(Q)*2+m2][n] = __builtin_amdgcn_mfma_f32_16x16x32_bf16(afr[m2][kk], bfr[n][kk], acc[(Q)*2+m2][n], 0,0,0); \
    } \
  } \
  __builtin_amdgcn_s_setprio(0); \
}while(0)

#define LGKM0() do{ \
  asm volatile("s_waitcnt lgkmcnt(0)" ::: "memory"); \
  __builtin_amdgcn_sched_barrier(0); \
}while(0)

template<int EPI>
DEVI void gtile256(const unsigned short* __restrict__ Ab,
                   const unsigned short* __restrict__ Bb,
                   const float* __restrict__ bias,
                   float* __restrict__ Cf, unsigned short* __restrict__ Ch,
                   int ldOut, int outRowBase, int col0, int K,
                   char* smem, int tid)
{
  int lane = tid & 63, w = tid >> 6;
  int lrow = lane & 15, lg = lane >> 4;
  int wm = w >> 2, wn = w & 3;
  f32x4 acc[8][4];
  #pragma unroll
  for (int i=0;i<8;i++){
    #pragma unroll
    for (int j=0;j<4;j++) acc[i][j] = f32x4{0.f,0.f,0.f,0.f};
  }
  int nkt = K >> 6;
  // half-tiles: H0 = A rows 0-127 (slot+0), H1 = A rows 128-255 (+16K),
  //             H2 = B rows 0-127 (+32K), H3 = B rows 128-255 (+48K)
  auto stage = [&](int kt2, int H){
    if (kt2 >= nkt) return;
    char* sl = smem + (kt2 & 1) * 65536 + H * 16384;
    int k0 = kt2 << 6;
    const unsigned short* src = (H < 2) ? Ab : Bb;
    int rbase = (H & 1) * 128;
    #pragma unroll
    for (int i=0;i<2;i++){
      int si = i*512 + tid;
      int r = si >> 3, kb = (si & 7) ^ (r & 7);
      gload_lds16(src + (size_t)(rbase + r)*K + k0 + kb*8, sl + si*16);
    }
  };
  // prologue: kt0 all 4 halves, kt1 B-lo/B-hi (kt1 A deferred to iter0 P0)
  stage(0,0); stage(0,1); stage(0,2); stage(0,3);
  stage(1,2); stage(1,3);
  asm volatile("s_waitcnt vmcnt(4)" ::: "memory");
  BAR();
  for (int kt = 0; kt < nkt; kt++){
    char* sA = smem + (kt & 1) * 65536;
    char* sB = sA + 32768;
    short8 bfr[4][2], afr[2][2];
    // ---- P0: read all B-frags + A quad0; stage kt+1 A-lo, A-hi
    #pragma unroll
    for (int n=0;n<4;n++){
      int ct = wn*64 + n*16 + lrow;
      #pragma unroll
      for (int kk=0;kk<2;kk++)
        bfr[n][kk] = *(const short8*)(sB + ct*128 + (((lg+kk*4)^(ct&7))<<4));
    }
    READ_AFR(0);
    stage(kt+1, 0); stage(kt+1, 1);
    BAR();
    LGKM0();
    QUADP(0);
    BAR();
    // ---- P1: A quad1; stage kt+2 B-lo
    READ_AFR(1);
    stage(kt+2, 2);
    BAR();
    LGKM0();
    QUADP(1);
    BAR();
    // ---- P2: A quad2; stage kt+2 B-hi
    READ_AFR(2);
    stage(kt+2, 3);
    BAR();
    LGKM0();
    QUADP(2);
    BAR();
    // ---- P3: A quad3; counted vmcnt (kt+1 must be fully landed)
    READ_AFR(3);
    if (kt + 2 < nkt) { asm volatile("s_waitcnt vmcnt(4)" ::: "memory"); }
    else              { asm volatile("s_waitcnt vmcnt(0)" ::: "memory"); }
    BAR();
    LGKM0();
    QUADP(3);
    BAR();
  }
  if constexpr (EPI == 2){
    #pragma unroll
    for (int m=0;m<8;m++){
      #pragma unroll
      for (int j=0;j<4;j++){
        int row = outRowBase + wm*128 + m*16 + lg*4 + j;
        #pragma unroll
        for (int nf=0;nf<4;nf+=2){
          int pcol = col0 + wn*64 + nf*16;
          int scol = ((pcol>>5)<<4) + lrow;
          float av = acc[m][nf][j]   + bias[scol];
          float gv = acc[m][nf+1][j] + bias[2048 + scol];
          float sg = gv / (1.f + __expf(-gv));
          Ch[(size_t)row*2048 + scol] = f2bf(av * sg);
        }
      }
    }
  } else {
    #pragma unroll
    for (int m=0;m<8;m++){
      #pragma unroll
      for (int j=0;j<4;j++){
        int row = outRowBase + wm*128 + m*16 + lg*4 + j;
        #pragma unroll
        for (int n=0;n<4;n++){
          int col = col0 + wn*64 + n*16 + lrow;
          float v = acc[m][n][j] + bias[col];
          if constexpr (EPI == 0) Cf[(size_t)row*ldOut + col] = v;
          else                    Ch[(size_t)row*ldOut + col] = f2bf(v);
        }
      }
    }
  }
}

// qkv GEMM: C fp32 [2048,1536] = xn @ wT_attn^T + bias
__global__ __launch_bounds__(512, 2)
void gemm256_f32(const unsigned short* __restrict__ A, const unsigned short* __restrict__ B,
                 const float* __restrict__ bias, float* __restrict__ Cf, int N, int K)
{
  __shared__ char smem[131072];
  gtile256<0>(A + (size_t)blockIdx.y*256*K, B + (size_t)blockIdx.x*256*K, bias,
              Cf, nullptr, N, blockIdx.y*256, blockIdx.x*256, K, smem, threadIdx.x);
}

// ---------------------------------------------------------------------------
// Legacy 128x128 GEMM for the small proj matmul: +resid, fp32+bf16 out
__global__ __launch_bounds__(256)
void gemm_proj(const unsigned short* __restrict__ A, const unsigned short* __restrict__ B,
               const float* __restrict__ bias,
               float* __restrict__ Cf, unsigned short* __restrict__ Ch,
               const float* __restrict__ resid, int M, int N, int K)
{
  __shared__ char smem[32768];
  char* smA = smem; char* smB = smem + 16384;
  int row0 = blockIdx.y * 128;
  int col0 = blockIdx.x * 128;
  int t = threadIdx.x, w = t>>6, lane = t&63;
  int lrow = lane&15, lg = lane>>4;
  int wr = w>>1, wc = w&1;

  f32x4 acc[4][4];
  #pragma unroll
  for (int i=0;i<4;i++){
    #pragma unroll
    for (int j=0;j<4;j++) acc[i][j] = f32x4{0.f,0.f,0.f,0.f};
  }
  const size_t Abase = (size_t)row0 * K;
  const size_t Bbase = (size_t)col0 * K;
  int nkt = K >> 6;
  for (int kt=0; kt<nkt; kt++){
    __syncthreads();
    int k0 = kt*64;
    #pragma unroll
    for (int i=0;i<4;i++){
      int s = (i*4 + w)*64 + lane;
      int r = s>>3;
      int kb = (s&7) ^ (r&7);
      gload_lds16(A + Abase + (size_t)r*K + k0 + kb*8, smA + (size_t)(i*4+w)*1024);
      gload_lds16(B + Bbase + (size_t)r*K + k0 + kb*8, smB + (size_t)(i*4+w)*1024);
    }
    __syncthreads();
    #pragma unroll
    for (int ks=0; ks<2; ks++){
      short8 af[4], bf[4];
      int kbb = lg + ks*4;
      #pragma unroll
      for (int m=0;m<4;m++){
        int rt = wr*64 + m*16 + lrow;
        af[m] = *(const short8*)(smA + rt*128 + ((kbb ^ (rt&7))<<4));
      }
      #pragma unroll
      for (int n=0;n<4;n++){
        int rt = wc*64 + n*16 + lrow;
        bf[n] = *(const short8*)(smB + rt*128 + ((kbb ^ (rt&7))<<4));
      }
      #pragma unroll
      for (int m=0;m<4;m++){
        #pragma unroll
        for (int n=0;n<4;n++)
          acc[m][n] = __builtin_amdgcn_mfma_f32_16x16x32_bf16(af[m], bf[n], acc[m][n], 0,0,0);
      }
    }
  }
  #pragma unroll
  for (int m=0;m<4;m++){
    int rloc = wr*64 + m*16 + lg*4;
    #pragma unroll
    for (int j=0;j<4;j++){
      int row = row0 + rloc + j;
      size_t rg = (size_t)row;
      #pragma unroll
      for (int n=0;n<4;n++){
        int col = col0 + wc*64 + n*16 + lrow;
        float v = acc[m][n][j] + bias[col];
        size_t idx = rg * N + col;
        v += resid[idx];
        Cf[idx] = v;
        Ch[idx] = f2bf(v);
      }
    }
  }
}

// ---------------------------------------------------------------------------
__global__ __launch_bounds__(256)
void prep_qkv(const float* __restrict__ qkv, const float* __restrict__ alpha,
              unsigned short* __restrict__ q_s, unsigned short* __restrict__ k_hat,
              unsigned short* __restrict__ v_t)
{
  int idx = blockIdx.x*4 + (threadIdx.x>>6);
  int lane = threadIdx.x & 63;
  int h = idx & 7, bt = idx >> 3;
  size_t base = (size_t)bt*1536 + h*64 + lane;
  float qv = qkv[base], kv = qkv[base+512], vv = qkv[base+1024];
  float qs2 = qv*qv, ks2 = kv*kv;
  #pragma unroll
  for (int m=1;m<64;m<<=1){ qs2 += __shfl_xor(qs2, m); ks2 += __shfl_xor(ks2, m); }
  float qh = qv / (sqrtf(qs2) + 1e-5f) * alpha[h];
  float kh = kv / (sqrtf(ks2) + 1e-5f);
  int b = bt >> 10, tt = bt & 1023;
  size_t hb = ((size_t)(b*8+h))*1024*64;
  q_s[hb + (size_t)tt*64 + lane] = f2bf(qh);
  k_hat[hb + (size_t)tt*64 + lane] = f2bf(kh);
  v_t[((size_t)(b*8+h)*64 + lane)*1024 + tt] = f2bf(vv);
}

// ---------------------------------------------------------------------------
__global__ __launch_bounds__(256)
void attn_k(const unsigned short* __restrict__ q_s, const unsigned short* __restrict__ k_hat,
            const unsigned short* __restrict__ v_t, unsigned short* __restrict__ y)
{
  __shared__ char sm[51200];
  char* smK = sm + 18432;
  char* smV = sm + 34816;
  int qt = blockIdx.x, bh = blockIdx.y;
  int b = bh>>3, h = bh&7;
  int t = threadIdx.x, w = t>>6, lane = t&63;
  int lrow = lane&15, lg = lane>>4;
  int q0 = qt*128;
  const size_t hQK = (size_t)bh*1024*64;
  const size_t hV  = (size_t)bh*64*1024;

  #pragma unroll
  for (int i=0;i<4;i++){
    int s = (i*4+w)*64 + lane;
    int r = s>>3, kb = (s&7)^(r&7);
    gload_lds16(q_s + hQK + (size_t)(q0+r)*64 + kb*8, sm + (size_t)(i*4+w)*1024);
  }
  __syncthreads();
  short8 qf[2][2];
  #pragma unroll
  for (int mf=0;mf<2;mf++){
    #pragma unroll
    for (int ks=0;ks<2;ks++){
      int rt = w*32 + mf*16 + lrow;
      int kbb = lg + ks*4;
      qf[mf][ks] = *(const short8*)(sm + rt*128 + ((kbb^(rt&7))<<4));
    }
  }
  f32x4 oacc[2][4];
  #pragma unroll
  for (int i=0;i<2;i++){
    #pragma unroll
    for (int j=0;j<4;j++) oacc[i][j] = f32x4{0.f,0.f,0.f,0.f};
  }
  float mrun[2][4], lrun[2][4];
  #pragma unroll
  for (int i=0;i<2;i++){
    #pragma unroll
    for (int j=0;j<4;j++){ mrun[i][j] = -1e30f; lrun[i][j] = 0.f; }
  }
  char* Pw = sm + w*4608;

  for (int kt=0; kt<=qt; kt++){
    __syncthreads();
    int t0 = kt*128;
    #pragma unroll
    for (int i=0;i<4;i++){
      int s = (i*4+w)*64 + lane;
      int r = s>>3, kb = (s&7)^(r&7);
      gload_lds16(k_hat + hQK + (size_t)(t0+r)*64 + kb*8, smK + (size_t)(i*4+w)*1024);
    }
    #pragma unroll
    for (int i=0;i<4;i++){
      int s = (i*4+w)*64 + lane;
      int d = s>>4, kb2 = s&15;
      int kb = kb2 ^ (d&7);
      gload_lds16(v_t + hV + (size_t)d*1024 + t0 + kb*8, smV + (size_t)(i*4+w)*1024);
    }
    __syncthreads();

    f32x4 sacc[2][8];
    #pragma unroll
    for (int i=0;i<2;i++){
      #pragma unroll
      for (int j=0;j<8;j++) sacc[i][j] = f32x4{0.f,0.f,0.f,0.f};
    }
    #pragma unroll
    for (int ks=0;ks<2;ks++){
      short8 kf[8];
      int kbb = lg + ks*4;
      #pragma unroll
      for (int nf=0;nf<8;nf++){
        int rt = nf*16+lrow;
        kf[nf] = *(const short8*)(smK + rt*128 + ((kbb^(rt&7))<<4));
      }
      #pragma unroll
      for (int mf=0;mf<2;mf++){
        #pragma unroll
        for (int nf=0;nf<8;nf++)
          sacc[mf][nf] = __builtin_amdgcn_mfma_f32_16x16x32_bf16(qf[mf][ks], kf[nf], sacc[mf][nf], 0,0,0);
      }
    }
    if (kt == qt){
      #pragma unroll
      for (int mf=0;mf<2;mf++){
        #pragma unroll
        for (int nf=0;nf<8;nf++){
          #pragma unroll
          for (int j=0;j<4;j++){
            int qi = w*32+mf*16+lg*4+j;
            int ki = nf*16 + lrow;
            if (ki > qi) sacc[mf][nf][j] = -1e30f;
          }
        }
      }
    }
    #pragma unroll
    for (int mf=0;mf<2;mf++){
      #pragma unroll
      for (int j=0;j<4;j++){
        float mx = sacc[mf][0][j];
        #pragma unroll
        for (int nf=1;nf<8;nf++) mx = fmaxf(mx, sacc[mf][nf][j]);
        #pragma unroll
        for (int m=1;m<16;m<<=1) mx = fmaxf(mx, __shfl_xor(mx, m));
        float mnew = fmaxf(mrun[mf][j], mx);
        float sc = __expf(mrun[mf][j] - mnew);
        float rs = 0.f;
        #pragma unroll
        for (int nf=0;nf<8;nf++){
          float p = __expf(sacc[mf][nf][j] - mnew);
          sacc[mf][nf][j] = p; rs += p;
        }
        #pragma unroll
        for (int m=1;m<16;m<<=1) rs += __shfl_xor(rs, m);
        lrun[mf][j] = lrun[mf][j]*sc + rs;
        mrun[mf][j] = mnew;
        #pragma unroll
        for (int n2=0;n2<4;n2++) oacc[mf][n2][j] *= sc;
      }
    }
    #pragma unroll
    for (int half=0; half<2; half++){
      #pragma unroll
      for (int mf=0;mf<2;mf++){
        #pragma unroll
        for (int nfh=0;nfh<4;nfh++){
          int nf = half*4 + nfh;
          #pragma unroll
          for (int j=0;j<4;j++){
            int row = mf*16 + lg*4 + j;
            int col = nfh*16 + lrow;
            *(unsigned short*)(Pw + (row*72 + col)*2) = f2bf(sacc[mf][nf][j]);
          }
        }
      }
      #pragma unroll
      for (int k2=0;k2<2;k2++){
        int ks2 = half*2 + k2;
        short8 pf[2], vf[4];
        #pragma unroll
        for (int mf=0;mf<2;mf++)
          pf[mf] = *(const short8*)(Pw + (mf*16+lrow)*144 + lg*16 + k2*64);
        #pragma unroll
        for (int n2=0;n2<4;n2++){
          int d = n2*16+lrow;
          int kbb2 = lg + ks2*4;
          vf[n2] = *(const short8*)(smV + d*256 + ((kbb2^(d&7))<<4));
        }
        #pragma unroll
        for (int mf=0;mf<2;mf++){
          #pragma unroll
          for (int n2=0;n2<4;n2++)
            oacc[mf][n2] = __builtin_amdgcn_mfma_f32_16x16x32_bf16(pf[mf], vf[n2], oacc[mf][n2], 0,0,0);
        }
      }
    }
  }
  #pragma unroll
  for (int mf=0;mf<2;mf++){
    #pragma unroll
    for (int n2=0;n2<4;n2++){
      #pragma unroll
      for (int j=0;j<4;j++){
        float v = oacc[mf][n2][j] / lrun[mf][j];
        int qi = q0 + w*32 + mf*16 + lg*4 + j;
        int d = n2*16 + lrow;
        y[((size_t)(b*1024+qi))*512 + h*64 + d] = f2bf(v);
      }
    }
  }
}

// ---------------------------------------------------------------------------
__global__ __launch_bounds__(256)
void router_topk(const float* __restrict__ x2f, const float* __restrict__ rw,
                 const float* __restrict__ rb, float* __restrict__ gates)
{
  int tkn = blockIdx.x*4 + (threadIdx.x>>6);
  int lane = threadIdx.x & 63;
  int e = lane & 15, p = lane >> 4;
  const float* xr = x2f + (size_t)tkn*512;
  float part = 0.f;
  for (int d = p*128; d < p*128+128; d++)
    part += xr[d] * rw[d*16 + e];
  part += __shfl_xor(part, 16);
  part += __shfl_xor(part, 32);
  float logit = part + rb[e];
  float mx = logit;
  #pragma unroll
  for (int m=1;m<16;m<<=1) mx = fmaxf(mx, __shfl_xor(mx, m));
  float ex = __expf(logit - mx);
  float sm = ex;
  #pragma unroll
  for (int m=1;m<16;m<<=1) sm += __shfl_xor(sm, m);
  float prob = ex / sm;
  bool taken = false;
  float ssum = 0.f;
  #pragma unroll
  for (int r=0;r<8;r++){
    float cv = taken ? -1.f : prob;
    int ci = e;
    #pragma unroll
    for (int m=1;m<16;m<<=1){
      float ov = __shfl_xor(cv, m);
      int oi = __shfl_xor(ci, m);
      if (ov > cv || (ov == cv && oi < ci)){ cv = ov; ci = oi; }
    }
    if (e == ci) taken = true;
    ssum += cv;
  }
  if (lane < 16)
    gates[(size_t)tkn*16 + e] = taken ? prob / ssum : 0.f;
}

// ---------------------------------------------------------------------------
__global__ void listbuild(const float* __restrict__ gates, int* __restrict__ list,
                          int* __restrict__ slot, int* __restrict__ cnt)
{
  int e = blockIdx.x;
  int tid = threadIdx.x, w = tid>>6, lane = tid&63;
  __shared__ int sbase;
  __shared__ int wsum[4];
  if (tid==0) sbase = 0;
  __syncthreads();
  for (int c=0;c<8;c++){
    int tk = c*256 + tid;
    bool flag = gates[(size_t)tk*16 + e] > 0.f;
    unsigned long long bal = __ballot(flag);
    if (lane==0) wsum[w] = (int)__popcll(bal);
    __syncthreads();
    int wpref = 0;
    for (int i=0;i<w;i++) wpref += wsum[i];
    int tot = wsum[0]+wsum[1]+wsum[2]+wsum[3];
    int lpref = (int)__popcll(bal & ((1ull<<lane)-1ull));
    if (flag){
      int pos = sbase + wpref + lpref;
      list[e*2048 + pos] = tk;
      slot[(size_t)tk*16 + e] = pos;
    }
    __syncthreads();
    if (tid==0) sbase += tot;
    __syncthreads();
  }
  if (tid==0) cnt[e] = sbase;
}

// off[] 256-aligned cumulative; zero the mega-kernel barrier counters
__global__ void prefix_off(const int* __restrict__ cnt, int* __restrict__ off,
                           int* __restrict__ bars){
  if (threadIdx.x==0 && blockIdx.x==0){
    int a=0;
    for (int e=0;e<16;e++){ off[e]=a; a += (cnt[e]+255)&~255; }
    off[16]=a;
    for (int i=0;i<8;i++) bars[i]=0;
  }
}

// ---------------------------------------------------------------------------
// Persistent expert mega-kernel: 256 blocks (1/CU), device spin barriers.
DEVI void gsync(int* bar){
  __syncthreads();
  if (threadIdx.x == 0){
    __threadfence();
    __hip_atomic_fetch_add(bar, 1, __ATOMIC_ACQ_REL, __HIP_MEMORY_SCOPE_AGENT);
    while (__hip_atomic_load(bar, __ATOMIC_ACQUIRE, __HIP_MEMORY_SCOPE_AGENT) < 256)
      __builtin_amdgcn_s_sleep(8);
  }
  __syncthreads();
  __threadfence();
}

__global__ __launch_bounds__(512, 2)
void moe_mega(const unsigned short* __restrict__ x2h,
              const int* __restrict__ list, const int* __restrict__ cnt,
              const int* __restrict__ off, const float* __restrict__ gates,
              const int* __restrict__ slot, const float* __restrict__ x2f,
              const unsigned short* __restrict__ wT_in, const float* __restrict__ b_in,
              const unsigned short* __restrict__ wT1p, const float* __restrict__ b1,
              const unsigned short* __restrict__ wT_2, const float* __restrict__ b2,
              const unsigned short* __restrict__ wT_out, const float* __restrict__ b_out,
              unsigned short* __restrict__ xe, unsigned short* __restrict__ hbuf,
              unsigned short* __restrict__ sbuf, unsigned short* __restrict__ obuf,
              unsigned short* __restrict__ eobuf, float* __restrict__ out,
              int* __restrict__ bars)
{
  __shared__ char smem[131072];
  __shared__ int soff[17];
  int tid = threadIdx.x, bid = blockIdx.x;
  if (tid < 17) soff[tid] = off[tid];
  __syncthreads();
  int rowsp = soff[16];
  int RT = rowsp >> 8;

  // stage 0: gather tokens -> xe (zero-fill pad rows)
  for (int r0 = bid*8; r0 < rowsp; r0 += 2048){
    int r = r0 + (tid>>6);
    if (r < rowsp){
      int e = 0;
      while (e < 15 && soff[e+1] <= r) e++;
      int s = r - soff[e];
      int lane8 = (tid&63)*8;
      short8 v = short8{0,0,0,0,0,0,0,0};
      if (s < cnt[e]){
        int tk = list[e*2048 + s];
        v = *(const short8*)(x2h + (size_t)tk*512 + lane8);
      }
      *(short8*)(xe + (size_t)r*512 + lane8) = v;
    }
  }
  gsync(bars+0);

  // stage 1: h = xe @ w_in + b_in   (K=512, N=2048)
  for (int t = bid; t < RT*8; t += 256){
    int rt = t >> 3, ct = t & 7;
    int row = rt << 8;
    int e = 0; while (e < 15 && soff[e+1] <= row) e++;
    gtile256<1>(xe + (size_t)row*512,
                wT_in + (size_t)e*2048*512 + (size_t)(ct*256)*512,
                b_in + e*2048, nullptr, hbuf, 2048, row, ct*256, 512, smem, tid);
  }
  gsync(bars+1);

  // stage 2: fused c1+c2+SwiGLU -> sbuf  (K=2048, permuted N=4096 -> 2048 out)
  for (int t = bid; t < RT*16; t += 256){
    int rt = t >> 4, ct = t & 15;
    int row = rt << 8;
    int e = 0; while (e < 15 && soff[e+1] <= row) e++;
    gtile256<2>(hbuf + (size_t)row*2048,
                wT1p + (size_t)e*4096*2048 + (size_t)(ct*256)*2048,
                b1 + e*4096, nullptr, sbuf, 2048, row, ct*256, 2048, smem, tid);
  }
  gsync(bars+2);

  // stage 3: o = s @ w2 + b2  (K=2048, N=2048)
  for (int t = bid; t < RT*8; t += 256){
    int rt = t >> 3, ct = t & 7;
    int row = rt << 8;
    int e = 0; while (e < 15 && soff[e+1] <= row) e++;
    gtile256<1>(sbuf + (size_t)row*2048,
                wT_2 + (size_t)e*2048*2048 + (size_t)(ct*256)*2048,
                b2 + e*2048, nullptr, obuf, 2048, row, ct*256, 2048, smem, tid);
  }
  gsync(bars+3);

  // stage 4: eo = o @ w_out + b_out  (K=2048, N=512)
  for (int t = bid; t < RT*2; t += 256){
    int rt = t >> 1, ct = t & 1;
    int row = rt << 8;
    int e = 0; while (e < 15 && soff[e+1] <= row) e++;
    gtile256<1>(obuf + (size_t)row*2048,
                wT_out + (size_t)e*512*2048 + (size_t)(ct*256)*2048,
                b_out + e*512, nullptr, eobuf, 512, row, ct*256, 2048, smem, tid);
  }
  gsync(bars+4);

  // stage 5: combine (one token per wave, 8 per block)
  {
    int tkn = bid*8 + (tid>>6);
    int lane8 = (tid&63)*8;
    float v[8];
    const float* xr = x2f + (size_t)tkn*512 + lane8;
    #pragma unroll
    for (int i=0;i<8;i++) v[i] = xr[i];
    for (int e=0;e<16;e++){
      float g = gates[(size_t)tkn*16 + e];
      if (g > 0.f){
        int rw = soff[e] + slot[(size_t)tkn*16 + e];
        short8 ev = *(const short8*)(eobuf + (size_t)rw*512 + lane8);
        #pragma unroll
        for (int i=0;i<8;i++) v[i] += g * bf2f((unsigned short)ev[i]);
      }
    }
    #pragma unroll
    for (int i=0;i<8;i++) out[(size_t)tkn*512 + lane8 + i] = v[i];
  }
}

// ---------------------------------------------------------------------------
extern "C" void kernel_launch(void* const* d_in, const int* in_sizes, int n_in,
                              void* d_out, int out_size, void* d_ws, size_t ws_size,
                              hipStream_t stream) {
  (void)in_sizes; (void)n_in; (void)out_size; (void)ws_size;
  const float* x    = (const float*)d_in[0];
  const float* gw   = (const float*)d_in[1];
  const float* bw   = (const float*)d_in[2];
  const float* caw  = (const float*)d_in[3];
  const float* cab  = (const float*)d_in[4];
  const float* alpha= (const float*)d_in[5];
  const float* cpw  = (const float*)d_in[6];
  const float* cpb  = (const float*)d_in[7];
  const float* rw   = (const float*)d_in[8];
  const float* rb   = (const float*)d_in[9];
  const float* w_in = (const float*)d_in[10];
  const float* b_in = (const float*)d_in[11];
  const float* w1   = (const float*)d_in[12];
  const float* b1   = (const float*)d_in[13];
  const float* w2   = (const float*)d_in[14];
  const float* b2   = (const float*)d_in[15];
  const float* w_out= (const float*)d_in[16];
  const float* b_out= (const float*)d_in[17];

  char* ws = (char*)d_ws;
  size_t o = 0;
  auto alloc = [&](size_t bytes)->char*{
    char* p = ws + o;
    o += (bytes + 255) & ~(size_t)255;
    return p;
  };
  const size_t PADROWS = 20480;  // sum of 256-aligned expert counts <= 16384+16*255
  unsigned short* wT_attn = (unsigned short*)alloc(1536ull*512*2);
  unsigned short* wT_proj = (unsigned short*)alloc(512ull*512*2);
  unsigned short* wT_in   = (unsigned short*)alloc(16ull*2048*512*2);
  unsigned short* wT1p    = (unsigned short*)alloc(16ull*4096*2048*2);
  unsigned short* wT_2    = (unsigned short*)alloc(16ull*2048*2048*2);
  unsigned short* wT_out  = (unsigned short*)alloc(16ull*512*2048*2);
  unsigned short* xn      = (unsigned short*)alloc(2048ull*512*2);
  float*          qkv     = (float*)alloc(2048ull*1536*4);
  unsigned short* q_s     = (unsigned short*)alloc(2048ull*512*2);
  unsigned short* k_hat   = (unsigned short*)alloc(2048ull*512*2);
  unsigned short* v_t     = (unsigned short*)alloc(2048ull*512*2);
  unsigned short* ybuf    = (unsigned short*)alloc(2048ull*512*2);
  float*          x2f     = (float*)alloc(2048ull*512*4);
  unsigned short* x2h     = (unsigned short*)alloc(2048ull*512*2);
  float*          gates   = (float*)alloc(2048ull*16*4);
  int*            slot    = (int*)alloc(2048ull*16*4);
  int*            list    = (int*)alloc(16ull*2048*4);
  int*            cnt     = (int*)alloc(64);
  int*            off     = (int*)alloc(256);
  int*            bars    = (int*)alloc(64);
  unsigned short* xe      = (unsigned short*)alloc(PADROWS*512*2);   // + eo alias
  unsigned short* hbuf    = (unsigned short*)alloc(PADROWS*2048*2);  // + o alias
  unsigned short* sbuf    = (unsigned short*)alloc(PADROWS*2048*2);
  unsigned short* eobuf   = xe;   // xe dead after h-GEMM
  unsigned short* obuf    = hbuf; // h dead after fused c1c2

  dim3 blk(256);
  dim3 blk5(512);
  // weight transposes fp32 -> bf16 [N][K]
  transpose_cvt<<<dim3(1536/32, 512/32, 1), blk, 0, stream>>>(caw, wT_attn, 512, 1536);
  transpose_cvt<<<dim3(512/32, 512/32, 1), blk, 0, stream>>>(cpw, wT_proj, 512, 512);
  transpose_cvt<<<dim3(2048/32, 512/32, 16), blk, 0, stream>>>(w_in, wT_in, 512, 2048);
  transpose_cvt_w1<<<dim3(4096/32, 2048/32, 16), blk, 0, stream>>>(w1, wT1p);
  transpose_cvt<<<dim3(2048/32, 2048/32, 16), blk, 0, stream>>>(w2, wT_2, 2048, 2048);
  transpose_cvt<<<dim3(512/32, 2048/32, 16), blk, 0, stream>>>(w_out, wT_out, 2048, 512);

  rmsnorm_k<<<512, blk, 0, stream>>>(x, gw, bw, xn);
  gemm256_f32<<<dim3(6, 8), blk5, 0, stream>>>(xn, wT_attn, cab, qkv, 1536, 512);
  prep_qkv<<<4096, blk, 0, stream>>>(qkv, alpha, q_s, k_hat, v_t);
  attn_k<<<dim3(8,16), blk, 0, stream>>>(q_s, k_hat, v_t, ybuf);
  gemm_proj<<<dim3(4,16,1), blk, 0, stream>>>(ybuf, wT_proj, cpb, x2f, x2h, x, 2048, 512, 512);
  router_topk<<<512, blk, 0, stream>>>(x2f, rw, rb, gates);
  listbuild<<<16, blk, 0, stream>>>(gates, list, slot, cnt);
  prefix_off<<<1, 64, 0, stream>>>(cnt, off, bars);

  moe_mega<<<256, blk5, 0, stream>>>(x2h, list, cnt, off, gates, slot, x2f,
                                     wT_in, b_in, wT1p, b1, wT_2, b2, wT_out, b_out,
                                     xe, hbuf, sbuf, obuf, eobuf, (float*)d_out, bars);
}

// Round 7
// 1186.627 us; speedup vs baseline: 1.7004x; 1.7004x over previous
//
#include <hip/hip_runtime.h>
#include <stdint.h>

#define DEVI __device__ __forceinline__
#define FENCE() asm volatile("" ::: "memory")

typedef short short8 __attribute__((ext_vector_type(8)));
typedef short short4v __attribute__((ext_vector_type(4)));
typedef float f32x4 __attribute__((ext_vector_type(4)));

DEVI float bf2f(unsigned short s){ union{unsigned u; float f;} x; x.u = ((unsigned)s)<<16; return x.f; }
DEVI unsigned short f2bf(float f){ union{float f; unsigned u;} x; x.f=f; unsigned r = x.u + 0x7fff + ((x.u>>16)&1); return (unsigned short)(r>>16); }

DEVI void gload_lds16(const void* g, void* l){
  __builtin_amdgcn_global_load_lds((const __attribute__((address_space(1))) unsigned int*)g,
                                   (__attribute__((address_space(3))) unsigned int*)l, 16, 0, 0);
}

// ---------------------------------------------------------------------------
// fp32 [K][N] (optionally batched z) -> bf16 [N][K]
__global__ __launch_bounds__(256)
void transpose_cvt(const float* __restrict__ in, unsigned short* __restrict__ out, int K, int N)
{
  __shared__ float tile[32][33];
  size_t zoff = (size_t)blockIdx.z * K * N;
  const float* src = in + zoff;
  unsigned short* dst = out + zoff;
  int kb = blockIdx.y*32, nb = blockIdx.x*32;
  int t = threadIdx.x;
  int tr = t>>3, tc = (t&7)*4;
  float4 v = *(const float4*)(src + (size_t)(kb+tr)*N + nb + tc);
  tile[tr][tc+0]=v.x; tile[tr][tc+1]=v.y; tile[tr][tc+2]=v.z; tile[tr][tc+3]=v.w;
  __syncthreads();
  short4v ov;
  ov[0] = (short)f2bf(tile[tc+0][tr]);
  ov[1] = (short)f2bf(tile[tc+1][tr]);
  ov[2] = (short)f2bf(tile[tc+2][tr]);
  ov[3] = (short)f2bf(tile[tc+3][tr]);
  *(short4v*)(dst + (size_t)(nb+tr)*K + kb + tc) = ov;
}

// ---------------------------------------------------------------------------
// w1 fp32 [2048][4096] -> permuted bf16 [4096][2048]: permuted row np holds
// source col c(np) = (np&16 ? 2048 : 0) + ((np>>5)<<4) + (np&15)
// (verified correct in rounds 5/6 mega runs)
__global__ __launch_bounds__(256)
void transpose_cvt_w1(const float* __restrict__ w1, unsigned short* __restrict__ outp)
{
  __shared__ float tile[32][33];
  int e = blockIdx.z;
  const float* src = w1 + (size_t)e*2048*4096;
  unsigned short* dst = outp + (size_t)e*4096*2048;
  int np0 = blockIdx.x*32;
  int k0 = blockIdx.y*32;
  int g = np0 >> 5;
  int t = threadIdx.x;
  int tr = t>>3, tc = (t&7)*4;
  int srccol = (tc < 16) ? (g*16 + tc) : (2048 + g*16 + (tc-16));
  float4 v = *(const float4*)(src + (size_t)(k0+tr)*4096 + srccol);
  tile[tr][tc+0]=v.x; tile[tr][tc+1]=v.y; tile[tr][tc+2]=v.z; tile[tr][tc+3]=v.w;
  __syncthreads();
  short4v ov;
  ov[0] = (short)f2bf(tile[tc+0][tr]);
  ov[1] = (short)f2bf(tile[tc+1][tr]);
  ov[2] = (short)f2bf(tile[tc+2][tr]);
  ov[3] = (short)f2bf(tile[tc+3][tr]);
  *(short4v*)(dst + (size_t)(np0+tr)*2048 + k0 + tc) = ov;
}

// ---------------------------------------------------------------------------
__global__ __launch_bounds__(256)
void rmsnorm_k(const float* __restrict__ x, const float* __restrict__ gw,
               const float* __restrict__ bw, unsigned short* __restrict__ xn)
{
  int row = blockIdx.x*4 + (threadIdx.x>>6);
  int lane = threadIdx.x & 63;
  const float* xr = x + (size_t)row*512 + lane*8;
  float4 a = *(const float4*)xr;
  float4 c = *(const float4*)(xr+4);
  float ss = a.x*a.x+a.y*a.y+a.z*a.z+a.w*a.w + c.x*c.x+c.y*c.y+c.z*c.z+c.w*c.w;
  #pragma unroll
  for (int m=1;m<64;m<<=1) ss += __shfl_xor(ss, m);
  float inv = 1.0f / sqrtf(ss*(1.f/512.f) + 1e-6f);
  const float* gr = gw + lane*8; const float* br = bw + lane*8;
  float4 g0=*(const float4*)gr, g1=*(const float4*)(gr+4);
  float4 b0=*(const float4*)br, b1=*(const float4*)(br+4);
  short8 o;
  o[0]=(short)f2bf(a.x*inv*g0.x + b0.x);
  o[1]=(short)f2bf(a.y*inv*g0.y + b0.y);
  o[2]=(short)f2bf(a.z*inv*g0.z + b0.z);
  o[3]=(short)f2bf(a.w*inv*g0.w + b0.w);
  o[4]=(short)f2bf(c.x*inv*g1.x + b1.x);
  o[5]=(short)f2bf(c.y*inv*g1.y + b1.y);
  o[6]=(short)f2bf(c.z*inv*g1.z + b1.z);
  o[7]=(short)f2bf(c.w*inv*g1.w + b1.w);
  *(short8*)(xn + (size_t)row*512 + lane*8) = o;
}

// ---------------------------------------------------------------------------
// Pipelined GEMM (round-2 proven engine): C[M,N] = A[M,K] * B^T, fp32 acc.
// 512 thr / 8 waves, tile 256x128, BK=64, 3 LDS slots (144KB), counted vmcnt,
// raw barriers, setprio around MFMA clusters, XCD-chunked block swizzle.
// EPI: 0 = fp32 out, 1 = bf16 out, 2 = fused SwiGLU (permuted W1, N=4096 in,
//      2048-col bf16 out; bias[0..2047]=a-bias, [2048..4095]=gate-bias)
template<int EPI>
__global__ __launch_bounds__(512, 2)
void gemm3(const unsigned short* __restrict__ A, const unsigned short* __restrict__ B,
           const float* __restrict__ bias,
           float* __restrict__ Cf, unsigned short* __restrict__ Ch,
           int M, int N, int K,
           const int* __restrict__ off, long long strideBz, long long strideBiasz)
{
  __shared__ char smem[147456];   // 3 slots x (A 256x64 + B 128x64) bf16
  // T1 XCD-chunked bijective swizzle (requires nwg % 8 == 0; all our grids are)
  int nbx = gridDim.x, nby = gridDim.y;
  int pl = nbx*nby;
  int lin = ((int)blockIdx.z*nby + (int)blockIdx.y)*nbx + (int)blockIdx.x;
  int nwg = pl*(int)gridDim.z;
  int cpx = nwg >> 3;
  int swz = (lin & 7)*cpx + (lin >> 3);
  int z  = swz / pl; int rxy = swz - z*pl;
  int by = rxy / nbx; int bx = rxy - by*nbx;

  int rowbase = 0, Mz = M;
  if (off){ rowbase = off[z]; Mz = off[z+1] - rowbase; }
  int row0 = by * 256;
  if (row0 >= Mz) return;
  int col0 = bx * 128;
  const unsigned short* Ab = A + (size_t)(rowbase + row0) * K;
  const unsigned short* Bb = B + (size_t)z * strideBz + (size_t)col0 * K;
  const float* biasz = bias + (size_t)z * strideBiasz;

  int tid = threadIdx.x;
  int lane = tid & 63, w = tid >> 6;
  int lrow = lane & 15, lg = lane >> 4;
  int wr = w >> 1, wc = w & 1;

  f32x4 acc[4][4];
  #pragma unroll
  for (int i=0;i<4;i++){
    #pragma unroll
    for (int j=0;j<4;j++) acc[i][j] = f32x4{0.f,0.f,0.f,0.f};
  }

  int nkt = K >> 6;

  auto stage = [&](int kt2, int part){
    if (kt2 >= nkt) return;
    char* sA = smem + (kt2 % 3) * 49152;
    char* sB = sA + 32768;
    int k0 = kt2 << 6;
    #pragma unroll
    for (int i=0;i<2;i++){
      int s = (part*2 + i)*512 + tid;
      int r = s >> 3, kb = (s & 7) ^ (r & 7);
      gload_lds16(Ab + (size_t)r*K + k0 + kb*8, sA + s*16);
    }
    {
      int s = part*512 + tid;
      int r = s >> 3, kb = (s & 7) ^ (r & 7);
      gload_lds16(Bb + (size_t)r*K + k0 + kb*8, sB + s*16);
    }
  };

  // prologue: K-tiles 0 and 1 (12 loads/thread); wait for K-tile 0 (6 left)
  stage(0,0); stage(0,1); stage(1,0); stage(1,1);
  asm volatile("s_waitcnt vmcnt(6)" ::: "memory");
  __builtin_amdgcn_s_barrier();
  FENCE();

  for (int kt = 0; kt < nkt; kt++){
    char* sA = smem + (kt % 3) * 49152;
    char* sB = sA + 32768;
    short8 bfr[4][2], afr[4][2];
    // ---- phase A: read all B-frags + A-frags m=0,1; stage half of kt+2
    #pragma unroll
    for (int n=0;n<4;n++){
      int ct = wc*64 + n*16 + lrow;
      #pragma unroll
      for (int kk=0;kk<2;kk++){
        int kbb = lg + kk*4;
        bfr[n][kk] = *(const short8*)(sB + ct*128 + ((kbb ^ (ct&7))<<4));
      }
    }
    #pragma unroll
    for (int m=0;m<2;m++){
      int rt = wr*64 + m*16 + lrow;
      #pragma unroll
      for (int kk=0;kk<2;kk++){
        int kbb = lg + kk*4;
        afr[m][kk] = *(const short8*)(sA + rt*128 + ((kbb ^ (rt&7))<<4));
      }
    }
    stage(kt+2, 0);
    FENCE(); __builtin_amdgcn_s_barrier(); FENCE();
    __builtin_amdgcn_s_setprio(1);
    #pragma unroll
    for (int m=0;m<2;m++){
      #pragma unroll
      for (int n=0;n<4;n++){
        #pragma unroll
        for (int kk=0;kk<2;kk++)
          acc[m][n] = __builtin_amdgcn_mfma_f32_16x16x32_bf16(afr[m][kk], bfr[n][kk], acc[m][n], 0,0,0);
      }
    }
    __builtin_amdgcn_s_setprio(0);
    FENCE(); __builtin_amdgcn_s_barrier(); FENCE();
    // ---- phase B: read A-frags m=2,3; stage other half of kt+2
    #pragma unroll
    for (int m=2;m<4;m++){
      int rt = wr*64 + m*16 + lrow;
      #pragma unroll
      for (int kk=0;kk<2;kk++){
        int kbb = lg + kk*4;
        afr[m][kk] = *(const short8*)(sA + rt*128 + ((kbb ^ (rt&7))<<4));
      }
    }
    stage(kt+2, 1);
    FENCE(); __builtin_amdgcn_s_barrier(); FENCE();
    __builtin_amdgcn_s_setprio(1);
    #pragma unroll
    for (int m=2;m<4;m++){
      #pragma unroll
      for (int n=0;n<4;n++){
        #pragma unroll
        for (int kk=0;kk<2;kk++)
          acc[m][n] = __builtin_amdgcn_mfma_f32_16x16x32_bf16(afr[m][kk], bfr[n][kk], acc[m][n], 0,0,0);
      }
    }
    __builtin_amdgcn_s_setprio(0);
    // counted vmcnt: guarantee K-tile kt+1 fully landed (conditional fixes the
    // latent no-op at kt = nkt-2 when stage(kt+2) was skipped)
    if (kt + 2 < nkt) { asm volatile("s_waitcnt vmcnt(6)" ::: "memory"); }
    else              { asm volatile("s_waitcnt vmcnt(0)" ::: "memory"); }
    FENCE(); __builtin_amdgcn_s_barrier(); FENCE();
  }

  #pragma unroll
  for (int m=0;m<4;m++){
    int rloc = wr*64 + m*16 + lg*4;
    #pragma unroll
    for (int j=0;j<4;j++){
      int row = row0 + rloc + j;
      if (row < Mz){
        size_t rg = (size_t)(rowbase + row);
        if constexpr (EPI == 2){
          #pragma unroll
          for (int nf=0;nf<4;nf+=2){
            int pcol = col0 + wc*64 + nf*16;
            int scol = ((pcol>>5)<<4) + lrow;
            float av = acc[m][nf][j]   + biasz[scol];
            float gv = acc[m][nf+1][j] + biasz[2048 + scol];
            float sg = gv / (1.f + __expf(-gv));
            Ch[rg*2048 + scol] = f2bf(av * sg);
          }
        } else {
          #pragma unroll
          for (int n=0;n<4;n++){
            int col = col0 + wc*64 + n*16 + lrow;
            float v = acc[m][n][j] + biasz[col];
            size_t idx = rg * N + col;
            if constexpr (EPI == 0) Cf[idx] = v;
            else                    Ch[idx] = f2bf(v);
          }
        }
      }
    }
  }
}

// ---------------------------------------------------------------------------
// Legacy 128x128 GEMM for the small proj matmul: +resid, fp32+bf16 out
__global__ __launch_bounds__(256)
void gemm_proj(const unsigned short* __restrict__ A, const unsigned short* __restrict__ B,
               const float* __restrict__ bias,
               float* __restrict__ Cf, unsigned short* __restrict__ Ch,
               const float* __restrict__ resid, int M, int N, int K)
{
  __shared__ char smem[32768];
  char* smA = smem; char* smB = smem + 16384;
  int row0 = blockIdx.y * 128;
  int col0 = blockIdx.x * 128;
  int t = threadIdx.x, w = t>>6, lane = t&63;
  int lrow = lane&15, lg = lane>>4;
  int wr = w>>1, wc = w&1;

  f32x4 acc[4][4];
  #pragma unroll
  for (int i=0;i<4;i++){
    #pragma unroll
    for (int j=0;j<4;j++) acc[i][j] = f32x4{0.f,0.f,0.f,0.f};
  }
  const size_t Abase = (size_t)row0 * K;
  const size_t Bbase = (size_t)col0 * K;
  int nkt = K >> 6;
  for (int kt=0; kt<nkt; kt++){
    __syncthreads();
    int k0 = kt*64;
    #pragma unroll
    for (int i=0;i<4;i++){
      int s = (i*4 + w)*64 + lane;
      int r = s>>3;
      int kb = (s&7) ^ (r&7);
      gload_lds16(A + Abase + (size_t)r*K + k0 + kb*8, smA + (size_t)(i*4+w)*1024);
      gload_lds16(B + Bbase + (size_t)r*K + k0 + kb*8, smB + (size_t)(i*4+w)*1024);
    }
    __syncthreads();
    #pragma unroll
    for (int ks=0; ks<2; ks++){
      short8 af[4], bf[4];
      int kbb = lg + ks*4;
      #pragma unroll
      for (int m=0;m<4;m++){
        int rt = wr*64 + m*16 + lrow;
        af[m] = *(const short8*)(smA + rt*128 + ((kbb ^ (rt&7))<<4));
      }
      #pragma unroll
      for (int n=0;n<4;n++){
        int rt = wc*64 + n*16 + lrow;
        bf[n] = *(const short8*)(smB + rt*128 + ((kbb ^ (rt&7))<<4));
      }
      #pragma unroll
      for (int m=0;m<4;m++){
        #pragma unroll
        for (int n=0;n<4;n++)
          acc[m][n] = __builtin_amdgcn_mfma_f32_16x16x32_bf16(af[m], bf[n], acc[m][n], 0,0,0);
      }
    }
  }
  #pragma unroll
  for (int m=0;m<4;m++){
    int rloc = wr*64 + m*16 + lg*4;
    #pragma unroll
    for (int j=0;j<4;j++){
      int row = row0 + rloc + j;
      size_t rg = (size_t)row;
      #pragma unroll
      for (int n=0;n<4;n++){
        int col = col0 + wc*64 + n*16 + lrow;
        float v = acc[m][n][j] + bias[col];
        size_t idx = rg * N + col;
        v += resid[idx];
        Cf[idx] = v;
        Ch[idx] = f2bf(v);
      }
    }
  }
}

// ---------------------------------------------------------------------------
__global__ __launch_bounds__(256)
void prep_qkv(const float* __restrict__ qkv, const float* __restrict__ alpha,
              unsigned short* __restrict__ q_s, unsigned short* __restrict__ k_hat,
              unsigned short* __restrict__ v_t)
{
  int idx = blockIdx.x*4 + (threadIdx.x>>6);
  int lane = threadIdx.x & 63;
  int h = idx & 7, bt = idx >> 3;
  size_t base = (size_t)bt*1536 + h*64 + lane;
  float qv = qkv[base], kv = qkv[base+512], vv = qkv[base+1024];
  float qs2 = qv*qv, ks2 = kv*kv;
  #pragma unroll
  for (int m=1;m<64;m<<=1){ qs2 += __shfl_xor(qs2, m); ks2 += __shfl_xor(ks2, m); }
  float qh = qv / (sqrtf(qs2) + 1e-5f) * alpha[h];
  float kh = kv / (sqrtf(ks2) + 1e-5f);
  int b = bt >> 10, tt = bt & 1023;
  size_t hb = ((size_t)(b*8+h))*1024*64;
  q_s[hb + (size_t)tt*64 + lane] = f2bf(qh);
  k_hat[hb + (size_t)tt*64 + lane] = f2bf(kh);
  v_t[((size_t)(b*8+h)*64 + lane)*1024 + tt] = f2bf(vv);
}

// ---------------------------------------------------------------------------
// Flash attention, 64-row q-tiles (grid 16x16 = 256 blocks for full GPU).
// Each wave owns 16 q-rows. K/V tiles 128 wide; causal: loop kt<=ktmax,
// mask only at the last (boundary) tile.
__global__ __launch_bounds__(256)
void attn_k(const unsigned short* __restrict__ q_s, const unsigned short* __restrict__ k_hat,
            const unsigned short* __restrict__ v_t, unsigned short* __restrict__ y)
{
  __shared__ char sm[51200];
  char* smK = sm + 18432;
  char* smV = sm + 34816;
  int qt = blockIdx.x, bh = blockIdx.y;
  int b = bh>>3, h = bh&7;
  int t = threadIdx.x, w = t>>6, lane = t&63;
  int lrow = lane&15, lg = lane>>4;
  int q0 = qt*64;
  const size_t hQK = (size_t)bh*1024*64;
  const size_t hV  = (size_t)bh*64*1024;

  // stage Q: 64 rows x 128B = 8KB
  #pragma unroll
  for (int i=0;i<2;i++){
    int si = i*256 + t;
    int r = si>>3, kb = (si&7)^(r&7);
    gload_lds16(q_s + hQK + (size_t)(q0+r)*64 + kb*8, sm + (size_t)si*16);
  }
  __syncthreads();
  short8 qf[2];
  #pragma unroll
  for (int ks=0;ks<2;ks++){
    int rt = w*16 + lrow;
    int kbb = lg + ks*4;
    qf[ks] = *(const short8*)(sm + rt*128 + ((kbb^(rt&7))<<4));
  }
  f32x4 oacc[4];
  #pragma unroll
  for (int j=0;j<4;j++) oacc[j] = f32x4{0.f,0.f,0.f,0.f};
  float mrun[4], lrun[4];
  #pragma unroll
  for (int j=0;j<4;j++){ mrun[j] = -1e30f; lrun[j] = 0.f; }
  char* Pw = sm + w*2304;   // 16 rows x 72 cols x 2B per wave (Q region is dead)

  int ktmax = (q0 + 63) >> 7;
  for (int kt=0; kt<=ktmax; kt++){
    __syncthreads();
    int t0 = kt*128;
    #pragma unroll
    for (int i=0;i<4;i++){
      int s = (i*4+w)*64 + lane;
      int r = s>>3, kb = (s&7)^(r&7);
      gload_lds16(k_hat + hQK + (size_t)(t0+r)*64 + kb*8, smK + (size_t)(i*4+w)*1024);
    }
    #pragma unroll
    for (int i=0;i<4;i++){
      int s = (i*4+w)*64 + lane;
      int d = s>>4, kb2 = s&15;
      int kb = kb2 ^ (d&7);
      gload_lds16(v_t + hV + (size_t)d*1024 + t0 + kb*8, smV + (size_t)(i*4+w)*1024);
    }
    __syncthreads();

    f32x4 sacc[8];
    #pragma unroll
    for (int j=0;j<8;j++) sacc[j] = f32x4{0.f,0.f,0.f,0.f};
    #pragma unroll
    for (int ks=0;ks<2;ks++){
      short8 kf[8];
      int kbb = lg + ks*4;
      #pragma unroll
      for (int nf=0;nf<8;nf++){
        int rt = nf*16+lrow;
        kf[nf] = *(const short8*)(smK + rt*128 + ((kbb^(rt&7))<<4));
      }
      #pragma unroll
      for (int nf=0;nf<8;nf++)
        sacc[nf] = __builtin_amdgcn_mfma_f32_16x16x32_bf16(qf[ks], kf[nf], sacc[nf], 0,0,0);
    }
    if (kt == ktmax){
      #pragma unroll
      for (int nf=0;nf<8;nf++){
        #pragma unroll
        for (int j=0;j<4;j++){
          int qi = q0 + w*16 + lg*4 + j;
          int ki = t0 + nf*16 + lrow;
          if (ki > qi) sacc[nf][j] = -1e30f;
        }
      }
    }
    #pragma unroll
    for (int j=0;j<4;j++){
      float mx = sacc[0][j];
      #pragma unroll
      for (int nf=1;nf<8;nf++) mx = fmaxf(mx, sacc[nf][j]);
      #pragma unroll
      for (int m=1;m<16;m<<=1) mx = fmaxf(mx, __shfl_xor(mx, m));
      float mnew = fmaxf(mrun[j], mx);
      float sc = __expf(mrun[j] - mnew);
      float rs = 0.f;
      #pragma unroll
      for (int nf=0;nf<8;nf++){
        float p = __expf(sacc[nf][j] - mnew);
        sacc[nf][j] = p; rs += p;
      }
      #pragma unroll
      for (int m=1;m<16;m<<=1) rs += __shfl_xor(rs, m);
      lrun[j] = lrun[j]*sc + rs;
      mrun[j] = mnew;
      #pragma unroll
      for (int n2=0;n2<4;n2++) oacc[n2][j] *= sc;
    }
    // PV in two 64-wide k halves via per-wave LDS P [16][72]
    #pragma unroll
    for (int half=0; half<2; half++){
      #pragma unroll
      for (int nfh=0;nfh<4;nfh++){
        int nf = half*4 + nfh;
        #pragma unroll
        for (int j=0;j<4;j++){
          int row = lg*4 + j;
          int col = nfh*16 + lrow;
          *(unsigned short*)(Pw + (row*72 + col)*2) = f2bf(sacc[nf][j]);
        }
      }
      #pragma unroll
      for (int k2=0;k2<2;k2++){
        int ks2 = half*2 + k2;
        short8 pf, vf[4];
        pf = *(const short8*)(Pw + lrow*144 + lg*16 + k2*64);
        #pragma unroll
        for (int n2=0;n2<4;n2++){
          int d = n2*16+lrow;
          int kbb2 = lg + ks2*4;
          vf[n2] = *(const short8*)(smV + d*256 + ((kbb2^(d&7))<<4));
        }
        #pragma unroll
        for (int n2=0;n2<4;n2++)
          oacc[n2] = __builtin_amdgcn_mfma_f32_16x16x32_bf16(pf, vf[n2], oacc[n2], 0,0,0);
      }
    }
  }
  #pragma unroll
  for (int n2=0;n2<4;n2++){
    #pragma unroll
    for (int j=0;j<4;j++){
      float v = oacc[n2][j] / lrun[j];
      int qi = q0 + w*16 + lg*4 + j;
      int d = n2*16 + lrow;
      y[((size_t)(b*1024+qi))*512 + h*64 + d] = f2bf(v);
    }
  }
}

// ---------------------------------------------------------------------------
__global__ __launch_bounds__(256)
void router_topk(const float* __restrict__ x2f, const float* __restrict__ rw,
                 const float* __restrict__ rb, float* __restrict__ gates)
{
  int tkn = blockIdx.x*4 + (threadIdx.x>>6);
  int lane = threadIdx.x & 63;
  int e = lane & 15, p = lane >> 4;
  const float* xr = x2f + (size_t)tkn*512;
  float part = 0.f;
  for (int d = p*128; d < p*128+128; d++)
    part += xr[d] * rw[d*16 + e];
  part += __shfl_xor(part, 16);
  part += __shfl_xor(part, 32);
  float logit = part + rb[e];
  float mx = logit;
  #pragma unroll
  for (int m=1;m<16;m<<=1) mx = fmaxf(mx, __shfl_xor(mx, m));
  float ex = __expf(logit - mx);
  float sm = ex;
  #pragma unroll
  for (int m=1;m<16;m<<=1) sm += __shfl_xor(sm, m);
  float prob = ex / sm;
  bool taken = false;
  float ssum = 0.f;
  #pragma unroll
  for (int r=0;r<8;r++){
    float cv = taken ? -1.f : prob;
    int ci = e;
    #pragma unroll
    for (int m=1;m<16;m<<=1){
      float ov = __shfl_xor(cv, m);
      int oi = __shfl_xor(ci, m);
      if (ov > cv || (ov == cv && oi < ci)){ cv = ov; ci = oi; }
    }
    if (e == ci) taken = true;
    ssum += cv;
  }
  if (lane < 16)
    gates[(size_t)tkn*16 + e] = taken ? prob / ssum : 0.f;
}

// ---------------------------------------------------------------------------
__global__ void listbuild(const float* __restrict__ gates, int* __restrict__ list,
                          int* __restrict__ slot, int* __restrict__ cnt)
{
  int e = blockIdx.x;
  int tid = threadIdx.x, w = tid>>6, lane = tid&63;
  __shared__ int sbase;
  __shared__ int wsum[4];
  if (tid==0) sbase = 0;
  __syncthreads();
  for (int c=0;c<8;c++){
    int tk = c*256 + tid;
    bool flag = gates[(size_t)tk*16 + e] > 0.f;
    unsigned long long bal = __ballot(flag);
    if (lane==0) wsum[w] = (int)__popcll(bal);
    __syncthreads();
    int wpref = 0;
    for (int i=0;i<w;i++) wpref += wsum[i];
    int tot = wsum[0]+wsum[1]+wsum[2]+wsum[3];
    int lpref = (int)__popcll(bal & ((1ull<<lane)-1ull));
    if (flag){
      int pos = sbase + wpref + lpref;
      list[e*2048 + pos] = tk;
      slot[(size_t)tk*16 + e] = pos;
    }
    __syncthreads();
    if (tid==0) sbase += tot;
    __syncthreads();
  }
  if (tid==0) cnt[e] = sbase;
}

__global__ void prefix_off(const int* __restrict__ cnt, int* __restrict__ off){
  if (threadIdx.x==0 && blockIdx.x==0){
    int a=0;
    for (int e=0;e<16;e++){ off[e]=a; a+=cnt[e]; }
    off[16]=a;
  }
}

__global__ __launch_bounds__(256)
void gather_rows(const unsigned short* __restrict__ x2h, const int* __restrict__ list,
                 const int* __restrict__ cnt, const int* __restrict__ off,
                 unsigned short* __restrict__ xe)
{
  int e = blockIdx.y;
  int s = blockIdx.x*4 + (threadIdx.x>>6);
  if (s >= cnt[e]) return;
  int lane = threadIdx.x & 63;
  int tk = list[e*2048 + s];
  *(short8*)(xe + ((size_t)(off[e]+s))*512 + lane*8) =
      *(const short8*)(x2h + (size_t)tk*512 + lane*8);
}

__global__ __launch_bounds__(256)
void combine_k(const float* __restrict__ x2f, const unsigned short* __restrict__ eo,
               const float* __restrict__ gates, const int* __restrict__ slot,
               const int* __restrict__ off, float* __restrict__ out)
{
  int tkn = blockIdx.x;
  __shared__ float gs[16];
  __shared__ int rws[16];
  int tid = threadIdx.x;
  if (tid < 16){
    float g = gates[(size_t)tkn*16 + tid];
    gs[tid] = g;
    rws[tid] = (g > 0.f) ? (off[tid] + slot[(size_t)tkn*16 + tid]) : 0;
  }
  __syncthreads();
  for (int d = tid; d < 512; d += 256){
    float v = x2f[(size_t)tkn*512 + d];
    #pragma unroll
    for (int e=0;e<16;e++){
      float g = gs[e];
      if (g > 0.f) v += g * bf2f(eo[(size_t)rws[e]*512 + d]);
    }
    out[(size_t)tkn*512 + d] = v;
  }
}

// ---------------------------------------------------------------------------
extern "C" void kernel_launch(void* const* d_in, const int* in_sizes, int n_in,
                              void* d_out, int out_size, void* d_ws, size_t ws_size,
                              hipStream_t stream) {
  (void)in_sizes; (void)n_in; (void)out_size; (void)ws_size;
  const float* x    = (const float*)d_in[0];
  const float* gw   = (const float*)d_in[1];
  const float* bw   = (const float*)d_in[2];
  const float* caw  = (const float*)d_in[3];
  const float* cab  = (const float*)d_in[4];
  const float* alpha= (const float*)d_in[5];
  const float* cpw  = (const float*)d_in[6];
  const float* cpb  = (const float*)d_in[7];
  const float* rw   = (const float*)d_in[8];
  const float* rb   = (const float*)d_in[9];
  const float* w_in = (const float*)d_in[10];
  const float* b_in = (const float*)d_in[11];
  const float* w1   = (const float*)d_in[12];
  const float* b1   = (const float*)d_in[13];
  const float* w2   = (const float*)d_in[14];
  const float* b2   = (const float*)d_in[15];
  const float* w_out= (const float*)d_in[16];
  const float* b_out= (const float*)d_in[17];

  char* ws = (char*)d_ws;
  size_t o = 0;
  auto alloc = [&](size_t bytes)->char*{
    char* p = ws + o;
    o += (bytes + 255) & ~(size_t)255;
    return p;
  };
  const size_t PADROWS = 16896;  // 16384 + 256-tile overread pad
  unsigned short* wT_attn = (unsigned short*)alloc(1536ull*512*2);
  unsigned short* wT_proj = (unsigned short*)alloc(512ull*512*2);
  unsigned short* wT_in   = (unsigned short*)alloc(16ull*2048*512*2);
  unsigned short* wT1p    = (unsigned short*)alloc(16ull*4096*2048*2);
  unsigned short* wT_2    = (unsigned short*)alloc(16ull*2048*2048*2);
  unsigned short* wT_out  = (unsigned short*)alloc(16ull*512*2048*2);
  unsigned short* xn      = (unsigned short*)alloc(2048ull*512*2);
  float*          qkv     = (float*)alloc(2048ull*1536*4);
  unsigned short* q_s     = (unsigned short*)alloc(2048ull*512*2);
  unsigned short* k_hat   = (unsigned short*)alloc(2048ull*512*2);
  unsigned short* v_t     = (unsigned short*)alloc(2048ull*512*2);
  unsigned short* ybuf    = (unsigned short*)alloc(2048ull*512*2);
  float*          x2f     = (float*)alloc(2048ull*512*4);
  unsigned short* x2h     = (unsigned short*)alloc(2048ull*512*2);
  float*          gates   = (float*)alloc(2048ull*16*4);
  int*            slot    = (int*)alloc(2048ull*16*4);
  int*            list    = (int*)alloc(16ull*2048*4);
  int*            cnt     = (int*)alloc(64);
  int*            off     = (int*)alloc(256);
  unsigned short* xe      = (unsigned short*)alloc(PADROWS*512*2);   // + eo alias
  unsigned short* hbuf    = (unsigned short*)alloc(PADROWS*2048*2);  // + o alias
  unsigned short* sbuf    = (unsigned short*)alloc(PADROWS*2048*2);
  unsigned short* eobuf   = xe;   // xe dead after h-GEMM
  unsigned short* obuf    = hbuf; // hbuf dead after fused SwiGLU GEMM

  dim3 blk(256);
  dim3 blk5(512);
  // weight transposes fp32 -> bf16 [N][K] (w1 -> permuted for fused SwiGLU)
  transpose_cvt<<<dim3(1536/32, 512/32, 1), blk, 0, stream>>>(caw, wT_attn, 512, 1536);
  transpose_cvt<<<dim3(512/32, 512/32, 1), blk, 0, stream>>>(cpw, wT_proj, 512, 512);
  transpose_cvt<<<dim3(2048/32, 512/32, 16), blk, 0, stream>>>(w_in, wT_in, 512, 2048);
  transpose_cvt_w1<<<dim3(4096/32, 2048/32, 16), blk, 0, stream>>>(w1, wT1p);
  transpose_cvt<<<dim3(2048/32, 2048/32, 16), blk, 0, stream>>>(w2, wT_2, 2048, 2048);
  transpose_cvt<<<dim3(512/32, 2048/32, 16), blk, 0, stream>>>(w_out, wT_out, 2048, 512);

  rmsnorm_k<<<512, blk, 0, stream>>>(x, gw, bw, xn);
  gemm3<0><<<dim3(12, 8, 1), blk5, 0, stream>>>(xn, wT_attn, cab, qkv, nullptr,
                                                2048, 1536, 512, nullptr, 0, 0);
  prep_qkv<<<4096, blk, 0, stream>>>(qkv, alpha, q_s, k_hat, v_t);
  attn_k<<<dim3(16,16), blk, 0, stream>>>(q_s, k_hat, v_t, ybuf);
  gemm_proj<<<dim3(4,16,1), blk, 0, stream>>>(ybuf, wT_proj, cpb, x2f, x2h, x, 2048, 512, 512);
  router_topk<<<512, blk, 0, stream>>>(x2f, rw, rb, gates);
  listbuild<<<16, blk, 0, stream>>>(gates, list, slot, cnt);
  prefix_off<<<1, 64, 0, stream>>>(cnt, off);
  gather_rows<<<dim3(512,16), blk, 0, stream>>>(x2h, list, cnt, off, xe);

  // experts (batched over z = expert, rows compacted via off[])
  gemm3<1><<<dim3(16,8,16), blk5, 0, stream>>>(xe, wT_in, b_in, nullptr, hbuf,
                                               0, 2048, 512, off, 2048ll*512, 2048);
  gemm3<2><<<dim3(32,8,16), blk5, 0, stream>>>(hbuf, wT1p, b1, nullptr, sbuf,
                                               0, 4096, 2048, off, 4096ll*2048, 4096);
  gemm3<1><<<dim3(16,8,16), blk5, 0, stream>>>(sbuf, wT_2, b2, nullptr, obuf,
                                               0, 2048, 2048, off, 2048ll*2048, 2048);
  gemm3<1><<<dim3(4,8,16), blk5, 0, stream>>>(obuf, wT_out, b_out, nullptr, eobuf,
                                              0, 512, 2048, off, 512ll*2048, 512);
  combine_k<<<2048, blk, 0, stream>>>(x2f, eobuf, gates, slot, off, (float*)d_out);
}

// Round 8
// 1108.744 us; speedup vs baseline: 1.8199x; 1.0702x over previous
//
#include <hip/hip_runtime.h>
#include <stdint.h>

#define DEVI __device__ __forceinline__
#define FENCE() asm volatile("" ::: "memory")
#define BAR() do{ FENCE(); __builtin_amdgcn_s_barrier(); FENCE(); }while(0)

typedef short short8 __attribute__((ext_vector_type(8)));
typedef short short4v __attribute__((ext_vector_type(4)));
typedef float f32x4 __attribute__((ext_vector_type(4)));

DEVI float bf2f(unsigned short s){ union{unsigned u; float f;} x; x.u = ((unsigned)s)<<16; return x.f; }
DEVI unsigned short f2bf(float f){ union{float f; unsigned u;} x; x.f=f; unsigned r = x.u + 0x7fff + ((x.u>>16)&1); return (unsigned short)(r>>16); }

DEVI void gload_lds16(const void* g, void* l){
  __builtin_amdgcn_global_load_lds((const __attribute__((address_space(1))) unsigned int*)g,
                                   (__attribute__((address_space(3))) unsigned int*)l, 16, 0, 0);
}

// ---------------------------------------------------------------------------
// fp32 [K][N] (optionally batched z) -> bf16 [N][K]
__global__ __launch_bounds__(256)
void transpose_cvt(const float* __restrict__ in, unsigned short* __restrict__ out, int K, int N)
{
  __shared__ float tile[32][33];
  size_t zoff = (size_t)blockIdx.z * K * N;
  const float* src = in + zoff;
  unsigned short* dst = out + zoff;
  int kb = blockIdx.y*32, nb = blockIdx.x*32;
  int t = threadIdx.x;
  int tr = t>>3, tc = (t&7)*4;
  float4 v = *(const float4*)(src + (size_t)(kb+tr)*N + nb + tc);
  tile[tr][tc+0]=v.x; tile[tr][tc+1]=v.y; tile[tr][tc+2]=v.z; tile[tr][tc+3]=v.w;
  __syncthreads();
  short4v ov;
  ov[0] = (short)f2bf(tile[tc+0][tr]);
  ov[1] = (short)f2bf(tile[tc+1][tr]);
  ov[2] = (short)f2bf(tile[tc+2][tr]);
  ov[3] = (short)f2bf(tile[tc+3][tr]);
  *(short4v*)(dst + (size_t)(nb+tr)*K + kb + tc) = ov;
}

// ---------------------------------------------------------------------------
// w1 fp32 [2048][4096] -> permuted bf16 [4096][2048]: permuted row np holds
// source col c(np) = (np&16 ? 2048 : 0) + ((np>>5)<<4) + (np&15)
__global__ __launch_bounds__(256)
void transpose_cvt_w1(const float* __restrict__ w1, unsigned short* __restrict__ outp)
{
  __shared__ float tile[32][33];
  int e = blockIdx.z;
  const float* src = w1 + (size_t)e*2048*4096;
  unsigned short* dst = outp + (size_t)e*4096*2048;
  int np0 = blockIdx.x*32;
  int k0 = blockIdx.y*32;
  int g = np0 >> 5;
  int t = threadIdx.x;
  int tr = t>>3, tc = (t&7)*4;
  int srccol = (tc < 16) ? (g*16 + tc) : (2048 + g*16 + (tc-16));
  float4 v = *(const float4*)(src + (size_t)(k0+tr)*4096 + srccol);
  tile[tr][tc+0]=v.x; tile[tr][tc+1]=v.y; tile[tr][tc+2]=v.z; tile[tr][tc+3]=v.w;
  __syncthreads();
  short4v ov;
  ov[0] = (short)f2bf(tile[tc+0][tr]);
  ov[1] = (short)f2bf(tile[tc+1][tr]);
  ov[2] = (short)f2bf(tile[tc+2][tr]);
  ov[3] = (short)f2bf(tile[tc+3][tr]);
  *(short4v*)(dst + (size_t)(np0+tr)*2048 + k0 + tc) = ov;
}

// ---------------------------------------------------------------------------
__global__ __launch_bounds__(256)
void rmsnorm_k(const float* __restrict__ x, const float* __restrict__ gw,
               const float* __restrict__ bw, unsigned short* __restrict__ xn)
{
  int row = blockIdx.x*4 + (threadIdx.x>>6);
  int lane = threadIdx.x & 63;
  const float* xr = x + (size_t)row*512 + lane*8;
  float4 a = *(const float4*)xr;
  float4 c = *(const float4*)(xr+4);
  float ss = a.x*a.x+a.y*a.y+a.z*a.z+a.w*a.w + c.x*c.x+c.y*c.y+c.z*c.z+c.w*c.w;
  #pragma unroll
  for (int m=1;m<64;m<<=1) ss += __shfl_xor(ss, m);
  float inv = 1.0f / sqrtf(ss*(1.f/512.f) + 1e-6f);
  const float* gr = gw + lane*8; const float* br = bw + lane*8;
  float4 g0=*(const float4*)gr, g1=*(const float4*)(gr+4);
  float4 b0=*(const float4*)br, b1=*(const float4*)(br+4);
  short8 o;
  o[0]=(short)f2bf(a.x*inv*g0.x + b0.x);
  o[1]=(short)f2bf(a.y*inv*g0.y + b0.y);
  o[2]=(short)f2bf(a.z*inv*g0.z + b0.z);
  o[3]=(short)f2bf(a.w*inv*g0.w + b0.w);
  o[4]=(short)f2bf(c.x*inv*g1.x + b1.x);
  o[5]=(short)f2bf(c.y*inv*g1.y + b1.y);
  o[6]=(short)f2bf(c.z*inv*g1.z + b1.z);
  o[7]=(short)f2bf(c.w*inv*g1.w + b1.w);
  *(short8*)(xn + (size_t)row*512 + lane*8) = o;
}

// ---------------------------------------------------------------------------
// m201-faithful 256x256 pipelined GEMM (dispatch form): 512 thr / 8 waves
// (2Mx4N), per-wave 128x64 out, BK=64, 2 LDS K-tile slots (128 KiB),
// 4 phases/K-tile: {1 A-quadrant ds_read (+all B in P0) || 1 half-tile stage
// -> bar -> lgkmcnt(0)+sched_barrier -> setprio 16xMFMA -> bar}.
// Counted vmcnt(4) at P3 (conditional drain at tail). Hazards:
//  - stage(kt+1,A) in P0 writes other slot; its readers finished iter kt-1 P3.
//  - stage(kt+2,B) in P1/P2 writes this slot's B; all B reads completed at
//    P0's lgkmcnt(0) + barrier.
// EPI: 0 = fp32 out + bias; 1 = bf16 out + bias; 2 = fused SwiGLU (permuted
//      W1, N=4096 acc -> 2048-col bf16 out; bias[0..2047]=a, [2048..]=gate)
#define READ_AFR(Q) do{ \
  _Pragma("unroll") \
  for (int m2=0;m2<2;m2++){ \
    int rt = wm*128 + ((Q)*2+m2)*16 + lrow; \
    _Pragma("unroll") \
    for (int kk=0;kk<2;kk++) \
      afr[m2][kk] = *(const short8*)(sA + rt*128 + (((lg+kk*4)^(rt&7))<<4)); \
  } \
}while(0)

#define QUADP(Q) do{ \
  __builtin_amdgcn_s_setprio(1); \
  _Pragma("unroll") \
  for (int m2=0;m2<2;m2++){ \
    _Pragma("unroll") \
    for (int n=0;n<4;n++){ \
      _Pragma("unroll") \
      for (int kk=0;kk<2;kk++) \
        acc[(Q)*2+m2][n] = __builtin_amdgcn_mfma_f32_16x16x32_bf16(afr[m2][kk], bfr[n][kk], acc[(Q)*2+m2][n], 0,0,0); \
    } \
  } \
  __builtin_amdgcn_s_setprio(0); \
}while(0)

#define LGKM0() do{ \
  asm volatile("s_waitcnt lgkmcnt(0)" ::: "memory"); \
  __builtin_amdgcn_sched_barrier(0); \
}while(0)

template<int EPI>
__global__ __launch_bounds__(512, 2)
void gemmT(const unsigned short* __restrict__ A, const unsigned short* __restrict__ B,
           const float* __restrict__ bias,
           float* __restrict__ Cf, unsigned short* __restrict__ Ch,
           int M, int N, int K,
           const int* __restrict__ off, long long strideBz, long long strideBiasz)
{
  __shared__ char smem[131072];
  int z = blockIdx.z;
  int rowbase = 0, Mz = M;
  if (off){ rowbase = off[z]; Mz = off[z+1] - rowbase; }
  int row0 = blockIdx.y * 256;
  if (row0 >= Mz) return;
  int col0 = blockIdx.x * 256;
  const unsigned short* Ab = A + (size_t)(rowbase + row0) * K;
  const unsigned short* Bb = B + (size_t)z * strideBz + (size_t)col0 * K;
  const float* biasz = bias + (size_t)z * strideBiasz;

  int tid = threadIdx.x;
  int lane = tid & 63, w = tid >> 6;
  int lrow = lane & 15, lg = lane >> 4;
  int wm = w >> 2, wn = w & 3;

  f32x4 acc[8][4];
  #pragma unroll
  for (int i=0;i<8;i++){
    #pragma unroll
    for (int j=0;j<4;j++) acc[i][j] = f32x4{0.f,0.f,0.f,0.f};
  }
  int nkt = K >> 6;
  // half-tiles: H0 = A rows 0-127, H1 = A rows 128-255, H2 = B 0-127, H3 = B 128-255
  auto stage = [&](int kt2, int H){
    if (kt2 >= nkt) return;
    char* sl = smem + (kt2 & 1) * 65536 + H * 16384;
    int k0 = kt2 << 6;
    const unsigned short* src = (H < 2) ? Ab : Bb;
    int rbase = (H & 1) * 128;
    #pragma unroll
    for (int i=0;i<2;i++){
      int si = i*512 + tid;
      int r = si >> 3, kb = (si & 7) ^ (r & 7);
      gload_lds16(src + (size_t)(rbase + r)*K + k0 + kb*8, sl + si*16);
    }
  };
  // prologue: kt0 all 4 halves + kt1 B-halves; kt1 A deferred to iter0 P0
  stage(0,0); stage(0,1); stage(0,2); stage(0,3);
  stage(1,2); stage(1,3);
  asm volatile("s_waitcnt vmcnt(4)" ::: "memory");
  BAR();
  for (int kt = 0; kt < nkt; kt++){
    char* sA = smem + (kt & 1) * 65536;
    char* sB = sA + 32768;
    short8 bfr[4][2], afr[2][2];
    // ---- P0: all B-frags + A quad0; stage kt+1 A-lo + A-hi
    #pragma unroll
    for (int n=0;n<4;n++){
      int ct = wn*64 + n*16 + lrow;
      #pragma unroll
      for (int kk=0;kk<2;kk++)
        bfr[n][kk] = *(const short8*)(sB + ct*128 + (((lg+kk*4)^(ct&7))<<4));
    }
    READ_AFR(0);
    stage(kt+1, 0); stage(kt+1, 1);
    BAR();
    LGKM0();
    QUADP(0);
    BAR();
    // ---- P1: A quad1; stage kt+2 B-lo
    READ_AFR(1);
    stage(kt+2, 2);
    BAR();
    LGKM0();
    QUADP(1);
    BAR();
    // ---- P2: A quad2; stage kt+2 B-hi
    READ_AFR(2);
    stage(kt+2, 3);
    BAR();
    LGKM0();
    QUADP(2);
    BAR();
    // ---- P3: A quad3; counted vmcnt guarantees kt+1 fully landed
    READ_AFR(3);
    if (kt + 2 < nkt) { asm volatile("s_waitcnt vmcnt(4)" ::: "memory"); }
    else              { asm volatile("s_waitcnt vmcnt(0)" ::: "memory"); }
    BAR();
    LGKM0();
    QUADP(3);
    BAR();
  }
  #pragma unroll
  for (int m=0;m<8;m++){
    #pragma unroll
    for (int j=0;j<4;j++){
      int row = row0 + wm*128 + m*16 + lg*4 + j;
      if (row < Mz){
        size_t rg = (size_t)(rowbase + row);
        if constexpr (EPI == 2){
          #pragma unroll
          for (int nf=0;nf<4;nf+=2){
            int pcol = col0 + wn*64 + nf*16;
            int scol = ((pcol>>5)<<4) + lrow;
            float av = acc[m][nf][j]   + biasz[scol];
            float gv = acc[m][nf+1][j] + biasz[2048 + scol];
            float sg = gv / (1.f + __expf(-gv));
            Ch[rg*2048 + scol] = f2bf(av * sg);
          }
        } else {
          #pragma unroll
          for (int n=0;n<4;n++){
            int col = col0 + wn*64 + n*16 + lrow;
            float v = acc[m][n][j] + biasz[col];
            size_t idx = rg * N + col;
            if constexpr (EPI == 0) Cf[idx] = v;
            else                    Ch[idx] = f2bf(v);
          }
        }
      }
    }
  }
}

// ---------------------------------------------------------------------------
// Legacy 128x128 GEMM for the small proj matmul: +resid, fp32+bf16 out
__global__ __launch_bounds__(256)
void gemm_proj(const unsigned short* __restrict__ A, const unsigned short* __restrict__ B,
               const float* __restrict__ bias,
               float* __restrict__ Cf, unsigned short* __restrict__ Ch,
               const float* __restrict__ resid, int M, int N, int K)
{
  __shared__ char smem[32768];
  char* smA = smem; char* smB = smem + 16384;
  int row0 = blockIdx.y * 128;
  int col0 = blockIdx.x * 128;
  int t = threadIdx.x, w = t>>6, lane = t&63;
  int lrow = lane&15, lg = lane>>4;
  int wr = w>>1, wc = w&1;

  f32x4 acc[4][4];
  #pragma unroll
  for (int i=0;i<4;i++){
    #pragma unroll
    for (int j=0;j<4;j++) acc[i][j] = f32x4{0.f,0.f,0.f,0.f};
  }
  const size_t Abase = (size_t)row0 * K;
  const size_t Bbase = (size_t)col0 * K;
  int nkt = K >> 6;
  for (int kt=0; kt<nkt; kt++){
    __syncthreads();
    int k0 = kt*64;
    #pragma unroll
    for (int i=0;i<4;i++){
      int s = (i*4 + w)*64 + lane;
      int r = s>>3;
      int kb = (s&7) ^ (r&7);
      gload_lds16(A + Abase + (size_t)r*K + k0 + kb*8, smA + (size_t)(i*4+w)*1024);
      gload_lds16(B + Bbase + (size_t)r*K + k0 + kb*8, smB + (size_t)(i*4+w)*1024);
    }
    __syncthreads();
    #pragma unroll
    for (int ks=0; ks<2; ks++){
      short8 af[4], bf[4];
      int kbb = lg + ks*4;
      #pragma unroll
      for (int m=0;m<4;m++){
        int rt = wr*64 + m*16 + lrow;
        af[m] = *(const short8*)(smA + rt*128 + ((kbb ^ (rt&7))<<4));
      }
      #pragma unroll
      for (int n=0;n<4;n++){
        int rt = wc*64 + n*16 + lrow;
        bf[n] = *(const short8*)(smB + rt*128 + ((kbb ^ (rt&7))<<4));
      }
      #pragma unroll
      for (int m=0;m<4;m++){
        #pragma unroll
        for (int n=0;n<4;n++)
          acc[m][n] = __builtin_amdgcn_mfma_f32_16x16x32_bf16(af[m], bf[n], acc[m][n], 0,0,0);
      }
    }
  }
  #pragma unroll
  for (int m=0;m<4;m++){
    int rloc = wr*64 + m*16 + lg*4;
    #pragma unroll
    for (int j=0;j<4;j++){
      int row = row0 + rloc + j;
      size_t rg = (size_t)row;
      #pragma unroll
      for (int n=0;n<4;n++){
        int col = col0 + wc*64 + n*16 + lrow;
        float v = acc[m][n][j] + bias[col];
        size_t idx = rg * N + col;
        v += resid[idx];
        Cf[idx] = v;
        Ch[idx] = f2bf(v);
      }
    }
  }
}

// ---------------------------------------------------------------------------
__global__ __launch_bounds__(256)
void prep_qkv(const float* __restrict__ qkv, const float* __restrict__ alpha,
              unsigned short* __restrict__ q_s, unsigned short* __restrict__ k_hat,
              unsigned short* __restrict__ v_t)
{
  int idx = blockIdx.x*4 + (threadIdx.x>>6);
  int lane = threadIdx.x & 63;
  int h = idx & 7, bt = idx >> 3;
  size_t base = (size_t)bt*1536 + h*64 + lane;
  float qv = qkv[base], kv = qkv[base+512], vv = qkv[base+1024];
  float qs2 = qv*qv, ks2 = kv*kv;
  #pragma unroll
  for (int m=1;m<64;m<<=1){ qs2 += __shfl_xor(qs2, m); ks2 += __shfl_xor(ks2, m); }
  float qh = qv / (sqrtf(qs2) + 1e-5f) * alpha[h];
  float kh = kv / (sqrtf(ks2) + 1e-5f);
  int b = bt >> 10, tt = bt & 1023;
  size_t hb = ((size_t)(b*8+h))*1024*64;
  q_s[hb + (size_t)tt*64 + lane] = f2bf(qh);
  k_hat[hb + (size_t)tt*64 + lane] = f2bf(kh);
  v_t[((size_t)(b*8+h)*64 + lane)*1024 + tt] = f2bf(vv);
}

// ---------------------------------------------------------------------------
// Flash attention, 64-row q-tiles (grid 16x16 = 256 blocks).
__global__ __launch_bounds__(256)
void attn_k(const unsigned short* __restrict__ q_s, const unsigned short* __restrict__ k_hat,
            const unsigned short* __restrict__ v_t, unsigned short* __restrict__ y)
{
  __shared__ char sm[51200];
  char* smK = sm + 18432;
  char* smV = sm + 34816;
  int qt = blockIdx.x, bh = blockIdx.y;
  int b = bh>>3, h = bh&7;
  int t = threadIdx.x, w = t>>6, lane = t&63;
  int lrow = lane&15, lg = lane>>4;
  int q0 = qt*64;
  const size_t hQK = (size_t)bh*1024*64;
  const size_t hV  = (size_t)bh*64*1024;

  #pragma unroll
  for (int i=0;i<2;i++){
    int si = i*256 + t;
    int r = si>>3, kb = (si&7)^(r&7);
    gload_lds16(q_s + hQK + (size_t)(q0+r)*64 + kb*8, sm + (size_t)si*16);
  }
  __syncthreads();
  short8 qf[2];
  #pragma unroll
  for (int ks=0;ks<2;ks++){
    int rt = w*16 + lrow;
    int kbb = lg + ks*4;
    qf[ks] = *(const short8*)(sm + rt*128 + ((kbb^(rt&7))<<4));
  }
  f32x4 oacc[4];
  #pragma unroll
  for (int j=0;j<4;j++) oacc[j] = f32x4{0.f,0.f,0.f,0.f};
  float mrun[4], lrun[4];
  #pragma unroll
  for (int j=0;j<4;j++){ mrun[j] = -1e30f; lrun[j] = 0.f; }
  char* Pw = sm + w*2304;

  int ktmax = (q0 + 63) >> 7;
  for (int kt=0; kt<=ktmax; kt++){
    __syncthreads();
    int t0 = kt*128;
    #pragma unroll
    for (int i=0;i<4;i++){
      int s = (i*4+w)*64 + lane;
      int r = s>>3, kb = (s&7)^(r&7);
      gload_lds16(k_hat + hQK + (size_t)(t0+r)*64 + kb*8, smK + (size_t)(i*4+w)*1024);
    }
    #pragma unroll
    for (int i=0;i<4;i++){
      int s = (i*4+w)*64 + lane;
      int d = s>>4, kb2 = s&15;
      int kb = kb2 ^ (d&7);
      gload_lds16(v_t + hV + (size_t)d*1024 + t0 + kb*8, smV + (size_t)(i*4+w)*1024);
    }
    __syncthreads();

    f32x4 sacc[8];
    #pragma unroll
    for (int j=0;j<8;j++) sacc[j] = f32x4{0.f,0.f,0.f,0.f};
    #pragma unroll
    for (int ks=0;ks<2;ks++){
      short8 kf[8];
      int kbb = lg + ks*4;
      #pragma unroll
      for (int nf=0;nf<8;nf++){
        int rt = nf*16+lrow;
        kf[nf] = *(const short8*)(smK + rt*128 + ((kbb^(rt&7))<<4));
      }
      #pragma unroll
      for (int nf=0;nf<8;nf++)
        sacc[nf] = __builtin_amdgcn_mfma_f32_16x16x32_bf16(qf[ks], kf[nf], sacc[nf], 0,0,0);
    }
    if (kt == ktmax){
      #pragma unroll
      for (int nf=0;nf<8;nf++){
        #pragma unroll
        for (int j=0;j<4;j++){
          int qi = q0 + w*16 + lg*4 + j;
          int ki = t0 + nf*16 + lrow;
          if (ki > qi) sacc[nf][j] = -1e30f;
        }
      }
    }
    #pragma unroll
    for (int j=0;j<4;j++){
      float mx = sacc[0][j];
      #pragma unroll
      for (int nf=1;nf<8;nf++) mx = fmaxf(mx, sacc[nf][j]);
      #pragma unroll
      for (int m=1;m<16;m<<=1) mx = fmaxf(mx, __shfl_xor(mx, m));
      float mnew = fmaxf(mrun[j], mx);
      float sc = __expf(mrun[j] - mnew);
      float rs = 0.f;
      #pragma unroll
      for (int nf=0;nf<8;nf++){
        float p = __expf(sacc[nf][j] - mnew);
        sacc[nf][j] = p; rs += p;
      }
      #pragma unroll
      for (int m=1;m<16;m<<=1) rs += __shfl_xor(rs, m);
      lrun[j] = lrun[j]*sc + rs;
      mrun[j] = mnew;
      #pragma unroll
      for (int n2=0;n2<4;n2++) oacc[n2][j] *= sc;
    }
    #pragma unroll
    for (int half=0; half<2; half++){
      #pragma unroll
      for (int nfh=0;nfh<4;nfh++){
        int nf = half*4 + nfh;
        #pragma unroll
        for (int j=0;j<4;j++){
          int row = lg*4 + j;
          int col = nfh*16 + lrow;
          *(unsigned short*)(Pw + (row*72 + col)*2) = f2bf(sacc[nf][j]);
        }
      }
      #pragma unroll
      for (int k2=0;k2<2;k2++){
        int ks2 = half*2 + k2;
        short8 pf, vf[4];
        pf = *(const short8*)(Pw + lrow*144 + lg*16 + k2*64);
        #pragma unroll
        for (int n2=0;n2<4;n2++){
          int d = n2*16+lrow;
          int kbb2 = lg + ks2*4;
          vf[n2] = *(const short8*)(smV + d*256 + ((kbb2^(d&7))<<4));
        }
        #pragma unroll
        for (int n2=0;n2<4;n2++)
          oacc[n2] = __builtin_amdgcn_mfma_f32_16x16x32_bf16(pf, vf[n2], oacc[n2], 0,0,0);
      }
    }
  }
  #pragma unroll
  for (int n2=0;n2<4;n2++){
    #pragma unroll
    for (int j=0;j<4;j++){
      float v = oacc[n2][j] / lrun[j];
      int qi = q0 + w*16 + lg*4 + j;
      int d = n2*16 + lrow;
      y[((size_t)(b*1024+qi))*512 + h*64 + d] = f2bf(v);
    }
  }
}

// ---------------------------------------------------------------------------
__global__ __launch_bounds__(256)
void router_topk(const float* __restrict__ x2f, const float* __restrict__ rw,
                 const float* __restrict__ rb, float* __restrict__ gates)
{
  int tkn = blockIdx.x*4 + (threadIdx.x>>6);
  int lane = threadIdx.x & 63;
  int e = lane & 15, p = lane >> 4;
  const float* xr = x2f + (size_t)tkn*512;
  float part = 0.f;
  for (int d = p*128; d < p*128+128; d++)
    part += xr[d] * rw[d*16 + e];
  part += __shfl_xor(part, 16);
  part += __shfl_xor(part, 32);
  float logit = part + rb[e];
  float mx = logit;
  #pragma unroll
  for (int m=1;m<16;m<<=1) mx = fmaxf(mx, __shfl_xor(mx, m));
  float ex = __expf(logit - mx);
  float sm = ex;
  #pragma unroll
  for (int m=1;m<16;m<<=1) sm += __shfl_xor(sm, m);
  float prob = ex / sm;
  bool taken = false;
  float ssum = 0.f;
  #pragma unroll
  for (int r=0;r<8;r++){
    float cv = taken ? -1.f : prob;
    int ci = e;
    #pragma unroll
    for (int m=1;m<16;m<<=1){
      float ov = __shfl_xor(cv, m);
      int oi = __shfl_xor(ci, m);
      if (ov > cv || (ov == cv && oi < ci)){ cv = ov; ci = oi; }
    }
    if (e == ci) taken = true;
    ssum += cv;
  }
  if (lane < 16)
    gates[(size_t)tkn*16 + e] = taken ? prob / ssum : 0.f;
}

// ---------------------------------------------------------------------------
__global__ void listbuild(const float* __restrict__ gates, int* __restrict__ list,
                          int* __restrict__ slot, int* __restrict__ cnt)
{
  int e = blockIdx.x;
  int tid = threadIdx.x, w = tid>>6, lane = tid&63;
  __shared__ int sbase;
  __shared__ int wsum[4];
  if (tid==0) sbase = 0;
  __syncthreads();
  for (int c=0;c<8;c++){
    int tk = c*256 + tid;
    bool flag = gates[(size_t)tk*16 + e] > 0.f;
    unsigned long long bal = __ballot(flag);
    if (lane==0) wsum[w] = (int)__popcll(bal);
    __syncthreads();
    int wpref = 0;
    for (int i=0;i<w;i++) wpref += wsum[i];
    int tot = wsum[0]+wsum[1]+wsum[2]+wsum[3];
    int lpref = (int)__popcll(bal & ((1ull<<lane)-1ull));
    if (flag){
      int pos = sbase + wpref + lpref;
      list[e*2048 + pos] = tk;
      slot[(size_t)tk*16 + e] = pos;
    }
    __syncthreads();
    if (tid==0) sbase += tot;
    __syncthreads();
  }
  if (tid==0) cnt[e] = sbase;
}

__global__ void prefix_off(const int* __restrict__ cnt, int* __restrict__ off){
  if (threadIdx.x==0 && blockIdx.x==0){
    int a=0;
    for (int e=0;e<16;e++){ off[e]=a; a+=cnt[e]; }
    off[16]=a;
  }
}

__global__ __launch_bounds__(256)
void gather_rows(const unsigned short* __restrict__ x2h, const int* __restrict__ list,
                 const int* __restrict__ cnt, const int* __restrict__ off,
                 unsigned short* __restrict__ xe)
{
  int e = blockIdx.y;
  int s = blockIdx.x*4 + (threadIdx.x>>6);
  if (s >= cnt[e]) return;
  int lane = threadIdx.x & 63;
  int tk = list[e*2048 + s];
  *(short8*)(xe + ((size_t)(off[e]+s))*512 + lane*8) =
      *(const short8*)(x2h + (size_t)tk*512 + lane*8);
}

__global__ __launch_bounds__(256)
void combine_k(const float* __restrict__ x2f, const unsigned short* __restrict__ eo,
               const float* __restrict__ gates, const int* __restrict__ slot,
               const int* __restrict__ off, float* __restrict__ out)
{
  int tkn = blockIdx.x;
  __shared__ float gs[16];
  __shared__ int rws[16];
  int tid = threadIdx.x;
  if (tid < 16){
    float g = gates[(size_t)tkn*16 + tid];
    gs[tid] = g;
    rws[tid] = (g > 0.f) ? (off[tid] + slot[(size_t)tkn*16 + tid]) : 0;
  }
  __syncthreads();
  for (int d = tid; d < 512; d += 256){
    float v = x2f[(size_t)tkn*512 + d];
    #pragma unroll
    for (int e=0;e<16;e++){
      float g = gs[e];
      if (g > 0.f) v += g * bf2f(eo[(size_t)rws[e]*512 + d]);
    }
    out[(size_t)tkn*512 + d] = v;
  }
}

// ---------------------------------------------------------------------------
extern "C" void kernel_launch(void* const* d_in, const int* in_sizes, int n_in,
                              void* d_out, int out_size, void* d_ws, size_t ws_size,
                              hipStream_t stream) {
  (void)in_sizes; (void)n_in; (void)out_size; (void)ws_size;
  const float* x    = (const float*)d_in[0];
  const float* gw   = (const float*)d_in[1];
  const float* bw   = (const float*)d_in[2];
  const float* caw  = (const float*)d_in[3];
  const float* cab  = (const float*)d_in[4];
  const float* alpha= (const float*)d_in[5];
  const float* cpw  = (const float*)d_in[6];
  const float* cpb  = (const float*)d_in[7];
  const float* rw   = (const float*)d_in[8];
  const float* rb   = (const float*)d_in[9];
  const float* w_in = (const float*)d_in[10];
  const float* b_in = (const float*)d_in[11];
  const float* w1   = (const float*)d_in[12];
  const float* b1   = (const float*)d_in[13];
  const float* w2   = (const float*)d_in[14];
  const float* b2   = (const float*)d_in[15];
  const float* w_out= (const float*)d_in[16];
  const float* b_out= (const float*)d_in[17];

  char* ws = (char*)d_ws;
  size_t o = 0;
  auto alloc = [&](size_t bytes)->char*{
    char* p = ws + o;
    o += (bytes + 255) & ~(size_t)255;
    return p;
  };
  const size_t PADROWS = 16896;  // 16384 + 256-tile overread pad
  unsigned short* wT_attn = (unsigned short*)alloc(1536ull*512*2);
  unsigned short* wT_proj = (unsigned short*)alloc(512ull*512*2);
  unsigned short* wT_in   = (unsigned short*)alloc(16ull*2048*512*2);
  unsigned short* wT1p    = (unsigned short*)alloc(16ull*4096*2048*2);
  unsigned short* wT_2    = (unsigned short*)alloc(16ull*2048*2048*2);
  unsigned short* wT_out  = (unsigned short*)alloc(16ull*512*2048*2);
  unsigned short* xn      = (unsigned short*)alloc(2048ull*512*2);
  float*          qkv     = (float*)alloc(2048ull*1536*4);
  unsigned short* q_s     = (unsigned short*)alloc(2048ull*512*2);
  unsigned short* k_hat   = (unsigned short*)alloc(2048ull*512*2);
  unsigned short* v_t     = (unsigned short*)alloc(2048ull*512*2);
  unsigned short* ybuf    = (unsigned short*)alloc(2048ull*512*2);
  float*          x2f     = (float*)alloc(2048ull*512*4);
  unsigned short* x2h     = (unsigned short*)alloc(2048ull*512*2);
  float*          gates   = (float*)alloc(2048ull*16*4);
  int*            slot    = (int*)alloc(2048ull*16*4);
  int*            list    = (int*)alloc(16ull*2048*4);
  int*            cnt     = (int*)alloc(64);
  int*            off     = (int*)alloc(256);
  unsigned short* xe      = (unsigned short*)alloc(PADROWS*512*2);   // + eo alias
  unsigned short* hbuf    = (unsigned short*)alloc(PADROWS*2048*2);  // + o alias
  unsigned short* sbuf    = (unsigned short*)alloc(PADROWS*2048*2);
  unsigned short* eobuf   = xe;   // xe dead after h-GEMM
  unsigned short* obuf    = hbuf; // hbuf dead after fused SwiGLU GEMM

  dim3 blk(256);
  dim3 blk5(512);
  // weight transposes fp32 -> bf16 [N][K] (w1 -> permuted for fused SwiGLU)
  transpose_cvt<<<dim3(1536/32, 512/32, 1), blk, 0, stream>>>(caw, wT_attn, 512, 1536);
  transpose_cvt<<<dim3(512/32, 512/32, 1), blk, 0, stream>>>(cpw, wT_proj, 512, 512);
  transpose_cvt<<<dim3(2048/32, 512/32, 16), blk, 0, stream>>>(w_in, wT_in, 512, 2048);
  transpose_cvt_w1<<<dim3(4096/32, 2048/32, 16), blk, 0, stream>>>(w1, wT1p);
  transpose_cvt<<<dim3(2048/32, 2048/32, 16), blk, 0, stream>>>(w2, wT_2, 2048, 2048);
  transpose_cvt<<<dim3(512/32, 2048/32, 16), blk, 0, stream>>>(w_out, wT_out, 2048, 512);

  rmsnorm_k<<<512, blk, 0, stream>>>(x, gw, bw, xn);
  gemmT<0><<<dim3(6, 8, 1), blk5, 0, stream>>>(xn, wT_attn, cab, qkv, nullptr,
                                               2048, 1536, 512, nullptr, 0, 0);
  prep_qkv<<<4096, blk, 0, stream>>>(qkv, alpha, q_s, k_hat, v_t);
  attn_k<<<dim3(16,16), blk, 0, stream>>>(q_s, k_hat, v_t, ybuf);
  gemm_proj<<<dim3(4,16,1), blk, 0, stream>>>(ybuf, wT_proj, cpb, x2f, x2h, x, 2048, 512, 512);
  router_topk<<<512, blk, 0, stream>>>(x2f, rw, rb, gates);
  listbuild<<<16, blk, 0, stream>>>(gates, list, slot, cnt);
  prefix_off<<<1, 64, 0, stream>>>(cnt, off);
  gather_rows<<<dim3(512,16), blk, 0, stream>>>(x2h, list, cnt, off, xe);

  // experts (batched over z = expert, rows compacted via off[])
  gemmT<1><<<dim3(8,8,16), blk5, 0, stream>>>(xe, wT_in, b_in, nullptr, hbuf,
                                              0, 2048, 512, off, 2048ll*512, 2048);
  gemmT<2><<<dim3(16,8,16), blk5, 0, stream>>>(hbuf, wT1p, b1, nullptr, sbuf,
                                               0, 4096, 2048, off, 4096ll*2048, 4096);
  gemmT<1><<<dim3(8,8,16), blk5, 0, stream>>>(sbuf, wT_2, b2, nullptr, obuf,
                                              0, 2048, 2048, off, 2048ll*2048, 2048);
  gemmT<1><<<dim3(2,8,16), blk5, 0, stream>>>(obuf, wT_out, b_out, nullptr, eobuf,
                                              0, 512, 2048, off, 512ll*2048, 512);
  combine_k<<<2048, blk, 0, stream>>>(x2f, eobuf, gates, slot, off, (float*)d_out);
}